// Round 11
// baseline (599.569 us; speedup 1.0000x reference)
//
#include <hip/hip_runtime.h>
#include <hip/hip_bf16.h>

#define H 128
#define NFEAT 10
#define EFEAT 10
#define XPS 144   // packed xp row stride in bf16: 128 vals + 8 f32 scores

typedef __attribute__((ext_vector_type(8))) short bf16x8;
typedef __attribute__((ext_vector_type(4))) float f32x4;
typedef __attribute__((ext_vector_type(16))) float f32x16;
typedef __attribute__((ext_vector_type(4))) unsigned u32x4;
typedef __attribute__((ext_vector_type(2))) unsigned u32x2;

__device__ __forceinline__ float bflo(unsigned v) { return __uint_as_float(v << 16); }
__device__ __forceinline__ float bfhi(unsigned v) { return __uint_as_float(v & 0xffff0000u); }
__device__ __forceinline__ unsigned bfpack(float a, float b) {
    __hip_bfloat16 h0 = __float2bfloat16(a), h1 = __float2bfloat16(b);
    return (unsigned)(*(unsigned short*)&h0) | ((unsigned)(*(unsigned short*)&h1) << 16);
}
__device__ __forceinline__ bf16x8 cast8(u32x4 v) { return __builtin_bit_cast(bf16x8, v); }

// Next-GEMM B-fragment from 8 acc-order packed words (verified, absmax 0.015625).
__device__ __forceinline__ bf16x8 frag_from_pack(const unsigned* w, int b2) {
    u32x4 t;
    t.x = w[b2 * 4 + 0];
    t.y = w[b2 * 4 + 1];
    t.z = w[b2 * 4 + 2];
    t.w = w[b2 * 4 + 3];
    return cast8(t);
}

// ---- deep-prefetch helpers: batch weight loads + batch MFMAs ----
__device__ __forceinline__ void ld8(bf16x8* dst, const __hip_bfloat16* base, int slot0, int l) {
#pragma unroll
    for (int i = 0; i < 8; i++)
        dst[i] = *(const bf16x8*)(base + ((size_t)(slot0 + i) * 64 + l) * 8);
}
__device__ __forceinline__ void ld4(bf16x8* dst, const __hip_bfloat16* base, int slot0, int l) {
#pragma unroll
    for (int i = 0; i < 4; i++)
        dst[i] = *(const bf16x8*)(base + ((size_t)(slot0 + i) * 64 + l) * 8);
}
__device__ __forceinline__ void mma8(f32x16* acc, const bf16x8* wb, bf16x8 bb0, bf16x8 bb1) {
#pragma unroll
    for (int mt = 0; mt < 4; mt++)
        acc[mt] = __builtin_amdgcn_mfma_f32_32x32x16_bf16(wb[mt], bb0, acc[mt], 0, 0, 0);
#pragma unroll
    for (int mt = 0; mt < 4; mt++)
        acc[mt] = __builtin_amdgcn_mfma_f32_32x32x16_bf16(wb[4 + mt], bb1, acc[mt], 0, 0, 0);
}
__device__ __forceinline__ void mma4x2(f32x16* acc, const bf16x8* wb, bf16x8 bb0, bf16x8 bb1) {
#pragma unroll
    for (int mt = 0; mt < 2; mt++)
        acc[mt] = __builtin_amdgcn_mfma_f32_32x32x16_bf16(wb[mt], bb0, acc[mt], 0, 0, 0);
#pragma unroll
    for (int mt = 0; mt < 2; mt++)
        acc[mt] = __builtin_amdgcn_mfma_f32_32x32x16_bf16(wb[2 + mt], bb1, acc[mt], 0, 0, 0);
}

// bias + LayerNorm + ReLU on NT 32x32 D-tiles, pack to acc-order bf16 words.
template<int NT>
__device__ __forceinline__ void bias_ln_relu_pack(f32x16* acc, const float* __restrict__ bias,
        const float* __restrict__ g, const float* __restrict__ beta,
        int hh, float invn, unsigned (*pk)[8]) {
    float sm = 0.f;
#pragma unroll
    for (int m = 0; m < NT; m++) {
#pragma unroll
        for (int P = 0; P < 4; P++) {
            f32x4 bv = *(const f32x4*)&bias[m * 32 + P * 8 + hh * 4];
#pragma unroll
            for (int u = 0; u < 4; u++) {
                float v = acc[m][P * 4 + u] + bv[u];
                acc[m][P * 4 + u] = v;
                sm += v;
            }
        }
    }
    sm += __shfl_xor(sm, 32, 64);
    float mean = sm * invn;
    float q = 0.f;
#pragma unroll
    for (int m = 0; m < NT; m++) {
#pragma unroll
        for (int r = 0; r < 16; r++) { float d = acc[m][r] - mean; q += d * d; }
    }
    q += __shfl_xor(q, 32, 64);
    float rstd = rsqrtf(q * invn + 1e-5f);
#pragma unroll
    for (int m = 0; m < NT; m++) {
#pragma unroll
        for (int P = 0; P < 4; P++) {
            f32x4 gv = *(const f32x4*)&g[m * 32 + P * 8 + hh * 4];
            f32x4 bz = *(const f32x4*)&beta[m * 32 + P * 8 + hh * 4];
#pragma unroll
            for (int u = 0; u < 4; u++) {
                float y = fmaxf((acc[m][P * 4 + u] - mean) * rstd * gv[u] + bz[u], 0.f);
                acc[m][P * 4 + u] = y;
            }
        }
    }
#pragma unroll
    for (int m = 0; m < NT; m++) {
#pragma unroll
        for (int p = 0; p < 8; p++) pk[m][p] = bfpack(acc[m][2 * p], acc[m][2 * p + 1]);
    }
}

// ---------------- fused front-end: wprep | degree | node_enc ------------------
__global__ __launch_bounds__(256) void k_front(
        const float* __restrict__ gate_w, const float* __restrict__ c1_w,
        const float* __restrict__ c2_w, const float* __restrict__ gatA_w,
        const float* __restrict__ gatB_w, const float* __restrict__ ee_w,
        __hip_bfloat16* __restrict__ gate_sw, __hip_bfloat16* __restrict__ c1_sw,
        __hip_bfloat16* __restrict__ c2_sw, __hip_bfloat16* __restrict__ wT3,
        __hip_bfloat16* __restrict__ ee_sw,
        const int* __restrict__ colp, int* __restrict__ deg,
        const float* __restrict__ x, const float* __restrict__ ne_w,
        const float* __restrict__ ne_b, const float* __restrict__ ne_g,
        const float* __restrict__ ne_beta, __hip_bfloat16* __restrict__ h,
        int E, int N, int nbWprep, int nbDeg) {
    int blk = blockIdx.x;
    if (blk < nbWprep) {
        int i = blk * 256 + threadIdx.x;
        if (i < 49152) {                       // gate: 96 frags (NMT=4, KS=24)
            int j = i & 7, l = (i >> 3) & 63, s = i >> 9;
            int m = s & 3, ks = s >> 2;
            int hh = l >> 5;
            int k;
            if (ks < 8) k = 256 + ks * 16 + 4 * hh + (j & 3) + 8 * (j >> 2);   // Ef (pack)
            else        k = (ks - 8) * 16 + hh * 8 + j;                         // S|D (mem)
            int n = m * 32 + (l & 31);
            gate_sw[i] = __float2bfloat16(gate_w[k * 128 + n]);
        } else if (i < 81920) {                // c1: 64 frags, pack-sourced
            int mm = i - 49152;
            int j = mm & 7, l = (mm >> 3) & 63, s = mm >> 9;
            int m = s & 3, ks = s >> 2;
            int k = ks * 16 + 4 * (l >> 5) + (j & 3) + 8 * (j >> 2);
            int n = m * 32 + (l & 31);
            c1_sw[mm] = __float2bfloat16(c1_w[k * 128 + n]);
        } else if (i < 90112) {                // c2: 16 frags, pack-sourced
            int mm = i - 81920;
            int j = mm & 7, l = (mm >> 3) & 63, s = mm >> 9;
            int m = s & 1, ks = s >> 1;
            int k = ks * 16 + 4 * (l >> 5) + (j & 3) + 8 * (j >> 2);
            int n = m * 32 + (l & 31);
            c2_sw[mm] = __float2bfloat16(c2_w[k * 64 + n]);
        } else if (i < 139264) {               // gatA[0], gatA[1], gatB
            int m = i - 90112;
            int mat = m / 16384, r = m % 16384;
            int n = r / 128, k = r % 128;
            const float* src = (mat < 2) ? (gatA_w + (size_t)mat * 16384) : gatB_w;
            wT3[m] = __float2bfloat16(src[k * 128 + n]);
        } else if (i < 141312) {               // ee: 4 frags, memory-sourced
            int mm = i - 139264;
            int j = mm & 7, l = (mm >> 3) & 63, s = mm >> 9;
            int k = (l >> 5) * 8 + j;
            int n = s * 32 + (l & 31);
            ee_sw[mm] = (k < EFEAT) ? __float2bfloat16(ee_w[k * 128 + n])
                                    : __float2bfloat16(0.0f);
        }
        return;
    }
    blk -= nbWprep;
    if (blk < nbDeg) {
        int i = blk * 256 + threadIdx.x;
        int E2 = E + N;
        if (i < E2) {
            int d = (i < E) ? colp[i] : (i - E);
            atomicAdd(&deg[d], 1);
        }
        return;
    }
    blk -= nbDeg;
    {
        int t = threadIdx.x;
        int w = t >> 6, l = t & 63;
        int n = blk * 4 + w;
        if (n >= N) return;
        float xs[NFEAT];
#pragma unroll
        for (int k = 0; k < NFEAT; k++) xs[k] = x[(size_t)n * NFEAT + k];
        float a0 = ne_b[2 * l], a1 = ne_b[2 * l + 1];
#pragma unroll
        for (int k = 0; k < NFEAT; k++) {
            float2 wv = *(const float2*)&ne_w[k * H + 2 * l];
            a0 += xs[k] * wv.x;
            a1 += xs[k] * wv.y;
        }
        float p = a0 + a1;
#pragma unroll
        for (int s = 1; s < 64; s <<= 1) p += __shfl_xor(p, s, 64);
        float mean = p * (1.0f / H);
        float d0 = a0 - mean, d1 = a1 - mean;
        float q = d0 * d0 + d1 * d1;
#pragma unroll
        for (int s = 1; s < 64; s <<= 1) q += __shfl_xor(q, s, 64);
        float rstd = rsqrtf(q * (1.0f / H) + 1e-5f);
        float y0 = fmaxf(d0 * rstd * ne_g[2 * l] + ne_beta[2 * l], 0.0f);
        float y1 = fmaxf(d1 * rstd * ne_g[2 * l + 1] + ne_beta[2 * l + 1], 0.0f);
        *(unsigned*)&h[(size_t)n * H + 2 * l] = bfpack(y0, y1);
    }
}

// ---------------- multi-block exclusive scan ----------------
__global__ __launch_bounds__(256) void k_scanA(const int* __restrict__ deg,
                                               int* __restrict__ bsum, int N) {
    __shared__ int s[256];
    int t = threadIdx.x;
    int i = blockIdx.x * 256 + t;
    s[t] = (i < N) ? deg[i] : 0;
    __syncthreads();
    for (int off = 128; off > 0; off >>= 1) {
        if (t < off) s[t] += s[t + off];
        __syncthreads();
    }
    if (t == 0) bsum[blockIdx.x] = s[0];
}

__global__ __launch_bounds__(1024) void k_scanB(int* __restrict__ bsum, int NB) {
    __shared__ int s[1024];
    int t = threadIdx.x;
    int v = (t < NB) ? bsum[t] : 0;
    s[t] = v;
    __syncthreads();
    for (int off = 1; off < 1024; off <<= 1) {
        int u = (t >= off) ? s[t - off] : 0;
        __syncthreads();
        s[t] += u;
        __syncthreads();
    }
    if (t < NB) bsum[t] = s[t] - v;   // exclusive prefix
}

// R11: also emits cursor2[n] = offs[n] - n  (exclusive prefix of indegree,
// i.e. CSR over REAL edges only — used to build the dst-sorted edge perm).
__global__ __launch_bounds__(256) void k_scanC(const int* __restrict__ deg,
                                               const int* __restrict__ bbase,
                                               int* __restrict__ offs,
                                               int* __restrict__ cursor,
                                               int* __restrict__ cursor2, int N) {
    __shared__ int s[256];
    int t = threadIdx.x;
    int i = blockIdx.x * 256 + t;
    int v = (i < N) ? deg[i] : 0;
    s[t] = v;
    __syncthreads();
    for (int off = 1; off < 256; off <<= 1) {
        int u = (t >= off) ? s[t - off] : 0;
        __syncthreads();
        s[t] += u;
        __syncthreads();
    }
    int incl = s[t];
    int base = bbase[blockIdx.x];
    if (i < N) {
        int e = base + incl - v;
        offs[i] = e;
        cursor[i] = e;
        cursor2[i] = e - i;        // deg2 = deg-1 (self-loop removed)
        if (i == N - 1) offs[N] = base + incl;
    }
}

// R11: also builds eperm — real edges sorted by destination.
__global__ __launch_bounds__(256) void k_scatter(const int* __restrict__ rowp,
                                                 const int* __restrict__ colp,
                                                 int* __restrict__ cursor,
                                                 int* __restrict__ cursor2,
                                                 int* __restrict__ srcs,
                                                 int* __restrict__ eperm,
                                                 int E, int N) {
    int i = blockIdx.x * blockDim.x + threadIdx.x;
    if (i < E + N) {
        int s, d;
        if (i < E) { s = rowp[i]; d = colp[i]; }
        else       { s = i - E;  d = i - E; }
        int pos = atomicAdd(&cursor[d], 1);
        srcs[pos] = s;
        if (i < E) {
            int p2 = atomicAdd(&cursor2[d], 1);
            eperm[p2] = i;
        }
    }
}

// ---------------- GAT stage 1: MFMA xp = h@w, fused scores ----------------
__global__ __launch_bounds__(256, 2) void k_gat_xp_mfma(
        const __hip_bfloat16* __restrict__ h_bf,
        const __hip_bfloat16* __restrict__ wT,
        const float* __restrict__ asrc,
        const float* __restrict__ adst,
        __hip_bfloat16* __restrict__ xp_bf,
        float* __restrict__ a_d,
        int heads, int N) {
    __shared__ __hip_bfloat16 Ws[128 * 136];
    __shared__ __hip_bfloat16 As[64 * 136];
    int t = threadIdx.x;
    int n0 = blockIdx.x * 64;

#pragma unroll
    for (int it = 0; it < 2; it++) {
        int idx = it * 256 + t;
        int row = idx >> 2, seg = idx & 3;
        const uint4* src = (const uint4*)(wT + row * 128 + seg * 32);
        uint4 v0 = src[0], v1 = src[1], v2 = src[2], v3 = src[3];
        uint4* dst = (uint4*)&Ws[row * 136 + seg * 32];
        dst[0] = v0; dst[1] = v1; dst[2] = v2; dst[3] = v3;
    }
    {
        int row = t >> 2, seg = t & 3;
        int n = n0 + row; if (n >= N) n = N - 1;
        const uint4* src = (const uint4*)(h_bf + (size_t)n * 128 + seg * 32);
        uint4 v0 = src[0], v1 = src[1], v2 = src[2], v3 = src[3];
        uint4* dst = (uint4*)&As[row * 136 + seg * 32];
        dst[0] = v0; dst[1] = v1; dst[2] = v2; dst[3] = v3;
    }
    __syncthreads();

    int w = t >> 6, l = t & 63, ln15 = l & 15, quad = l >> 4, q8 = quad * 8;
    f32x4 acc[8] = {};
#pragma unroll
    for (int k = 0; k < 128; k += 32) {
        bf16x8 af = *(const bf16x8*)&As[(w * 16 + ln15) * 136 + k + q8];
#pragma unroll
        for (int i = 0; i < 8; i++) {
            bf16x8 bfr = *(const bf16x8*)&Ws[(i * 16 + ln15) * 136 + k + q8];
            acc[i] = __builtin_amdgcn_mfma_f32_16x16x32_bf16(af, bfr, acc[i], 0, 0, 0);
        }
    }

    if (heads == 8) {
#pragma unroll
        for (int i = 0; i < 8; i++) {
            float av = asrc[i * 16 + ln15], dvv = adst[i * 16 + ln15];
            float ps[4], pd[4];
#pragma unroll
            for (int r = 0; r < 4; r++) { ps[r] = acc[i][r] * av; pd[r] = acc[i][r] * dvv; }
#pragma unroll
            for (int s = 1; s < 16; s <<= 1) {
#pragma unroll
                for (int r = 0; r < 4; r++) {
                    ps[r] += __shfl_xor(ps[r], s, 64);
                    pd[r] += __shfl_xor(pd[r], s, 64);
                }
            }
            if (ln15 == 0) {
#pragma unroll
                for (int r = 0; r < 4; r++) {
                    int n = n0 + w * 16 + quad * 4 + r;
                    if (n < N) {
                        *(float*)&xp_bf[(size_t)n * XPS + 128 + 2 * i] = ps[r];
                        a_d[(size_t)n * 8 + i] = pd[r];
                    }
                }
            }
        }
    } else {
        float ps[4] = {0, 0, 0, 0}, pd[4] = {0, 0, 0, 0};
#pragma unroll
        for (int i = 0; i < 8; i++) {
            float av = asrc[i * 16 + ln15], dvv = adst[i * 16 + ln15];
#pragma unroll
            for (int r = 0; r < 4; r++) { ps[r] += acc[i][r] * av; pd[r] += acc[i][r] * dvv; }
        }
#pragma unroll
        for (int s = 1; s < 16; s <<= 1) {
#pragma unroll
            for (int r = 0; r < 4; r++) {
                ps[r] += __shfl_xor(ps[r], s, 64);
                pd[r] += __shfl_xor(pd[r], s, 64);
            }
        }
        if (ln15 == 0) {
#pragma unroll
            for (int r = 0; r < 4; r++) {
                int n = n0 + w * 16 + quad * 4 + r;
                if (n < N) {
                    *(float*)&xp_bf[(size_t)n * XPS + 128] = ps[r];
                    a_d[n] = pd[r];
                }
            }
        }
    }

#pragma unroll
    for (int i = 0; i < 8; i++) {
#pragma unroll
        for (int r = 0; r < 4; r++) {
            int n = n0 + w * 16 + quad * 4 + r;
            if (n < N) xp_bf[(size_t)n * XPS + i * 16 + ln15] = __float2bfloat16(acc[i][r]);
        }
    }
}

// ---------------- GAT stage 2: 1 wave/node, packed-row gather (R8 8-batch) ----
__global__ __launch_bounds__(256) void k_gat_agg(const __hip_bfloat16* __restrict__ xp,
                                                 const float* __restrict__ a_d,
                                                 const int* __restrict__ offs,
                                                 const int* __restrict__ srcs,
                                                 const float* __restrict__ bias,
                                                 const float* __restrict__ g,
                                                 const float* __restrict__ b,
                                                 __hip_bfloat16* __restrict__ hout,
                                                 int heads, int N) {
    int t = threadIdx.x;
    int w = t >> 6, l = t & 63;
    int n = blockIdx.x * 4 + w;
    if (n >= N) return;
    int head = (heads == 8) ? (l >> 3) : 0;
    float adv = a_d[(size_t)n * heads + head];
    int s0 = offs[n], s1 = offs[n + 1];
    float acc0 = 0.0f, acc1 = 0.0f, den = 0.0f;
    int j = s0;
    for (; j + 8 <= s1; j += 8) {
        int s_[8];
#pragma unroll
        for (int u = 0; u < 8; u++) s_[u] = srcs[j + u];
        float e_[8]; unsigned v_[8];
#pragma unroll
        for (int u = 0; u < 8; u++) {
            const __hip_bfloat16* xr = xp + (size_t)s_[u] * XPS;
            e_[u] = ((const float*)xr)[64 + head];
            v_[u] = *(const unsigned*)&xr[2 * l];
        }
#pragma unroll
        for (int u = 0; u < 8; u++) {
            float e = e_[u] + adv;
            e = (e >= 0.0f) ? e : 0.2f * e;
            float ex = __expf(e);
            den += ex;
            acc0 += ex * bflo(v_[u]);
            acc1 += ex * bfhi(v_[u]);
        }
    }
    for (; j + 4 <= s1; j += 4) {
        int s_[4];
#pragma unroll
        for (int u = 0; u < 4; u++) s_[u] = srcs[j + u];
        float e_[4]; unsigned v_[4];
#pragma unroll
        for (int u = 0; u < 4; u++) {
            const __hip_bfloat16* xr = xp + (size_t)s_[u] * XPS;
            e_[u] = ((const float*)xr)[64 + head];
            v_[u] = *(const unsigned*)&xr[2 * l];
        }
#pragma unroll
        for (int u = 0; u < 4; u++) {
            float e = e_[u] + adv;
            e = (e >= 0.0f) ? e : 0.2f * e;
            float ex = __expf(e);
            den += ex;
            acc0 += ex * bflo(v_[u]);
            acc1 += ex * bfhi(v_[u]);
        }
    }
    for (; j < s1; j++) {
        int s = srcs[j];
        const __hip_bfloat16* xr = xp + (size_t)s * XPS;
        float e = ((const float*)xr)[64 + head] + adv;
        e = (e >= 0.0f) ? e : 0.2f * e;
        float ex = __expf(e);
        den += ex;
        unsigned v = *(const unsigned*)&xr[2 * l];
        acc0 += ex * bflo(v);
        acc1 += ex * bfhi(v);
    }
    float inv = 1.0f / den;
    float v0 = acc0 * inv + bias[2 * l];
    float v1 = acc1 * inv + bias[2 * l + 1];
    float p = v0 + v1;
#pragma unroll
    for (int s = 1; s < 64; s <<= 1) p += __shfl_xor(p, s, 64);
    float mean = p * (1.0f / H);
    float d0 = v0 - mean, d1 = v1 - mean;
    float q = d0 * d0 + d1 * d1;
#pragma unroll
    for (int s = 1; s < 64; s <<= 1) q += __shfl_xor(q, s, 64);
    float rstd = rsqrtf(q * (1.0f / H) + 1e-5f);
    float y0 = fmaxf(d0 * rstd * g[2 * l] + b[2 * l], 0.0f);
    float y1 = fmaxf(d1 * rstd * g[2 * l + 1] + b[2 * l + 1], 0.0f);
    *(unsigned*)&hout[(size_t)n * H + 2 * l] = bfpack(y0, y1);
}

// ---------------- Edge classifier (R4 math, R11: dst-sorted edge order) ------
// Processes edges via eperm (CSR/dst-sorted): consecutive lanes share dst ->
// rD gathers collapse to broadcasts/L1 hits (~400k random rows -> ~50k).
// Per-edge math identical to R4/R8 -> absmax unchanged.
__global__ __launch_bounds__(256, 2) void k_edge_cls_mfma32(
        const __hip_bfloat16* __restrict__ h_bf,
        const int* __restrict__ rowp, const int* __restrict__ colp,
        const int* __restrict__ eperm,
        const float* __restrict__ eattr,
        const __hip_bfloat16* __restrict__ ee_fa, const float* __restrict__ ee_b,
        const float* __restrict__ ee_g, const float* __restrict__ ee_beta,
        const __hip_bfloat16* __restrict__ gate_fa, const float* __restrict__ gate_b,
        const __hip_bfloat16* __restrict__ c1_fa, const float* __restrict__ c1_b,
        const float* __restrict__ cl1_g, const float* __restrict__ cl1_b,
        const __hip_bfloat16* __restrict__ c2_fa, const float* __restrict__ c2_b,
        const float* __restrict__ cl2_g, const float* __restrict__ cl2_b,
        const float* __restrict__ c3_w, const float* __restrict__ c3_b,
        float* __restrict__ out, int E) {
    int t = threadIdx.x;
    int w = t >> 6, l = t & 63;
    int hh = l >> 5, e32 = l & 31;
    int pIdx = blockIdx.x * 128 + w * 32 + e32;
    int pF = (pIdx < E) ? pIdx : (E - 1);
    int eF = eperm[pF];
    int ri = rowp[eF], ci = colp[eF];
    const unsigned short* rS = (const unsigned short*)h_bf + (size_t)ri * H;
    const unsigned short* rD = (const unsigned short*)h_bf + (size_t)ci * H;

    bf16x8 wbA[8], wbB[8];

    // ---- GEMM0: Ef = relu(LN(ea @ ee_w + ee_b)), kept as packed words efw ----
    unsigned efw[4][8];
    {
        const char* eb = (const char*)(eattr + (size_t)eF * EFEAT);
        float2 p0 = *(const float2*)(eb + (hh << 5));
        float2 p1 = *(const float2*)(eb + 8);
        float2 p2 = *(const float2*)(eb + 16);
        float2 p3 = *(const float2*)(eb + 24);
        bf16x8 eef[4];
        ld4(eef, ee_fa, 0, l);
        if (hh) { p1.x = p1.y = 0.f; p2.x = p2.y = 0.f; p3.x = p3.y = 0.f; }
        u32x4 bwv;
        bwv.x = bfpack(p0.x, p0.y);
        bwv.y = bfpack(p1.x, p1.y);
        bwv.z = bfpack(p2.x, p2.y);
        bwv.w = bfpack(p3.x, p3.y);
        bf16x8 bb = cast8(bwv);
        f32x16 acc[4] = {};
#pragma unroll
        for (int m = 0; m < 4; m++)
            acc[m] = __builtin_amdgcn_mfma_f32_32x32x16_bf16(eef[m], bb, acc[m], 0, 0, 0);
        ld8(wbA, gate_fa, 0, l);             // GEMM1 batch0 — hidden under LN-pack
        bias_ln_relu_pack<4>(acc, ee_b, ee_g, ee_beta, hh, 1.f / 128.f, efw);
    }

    // ---- GEMM1: gate = sigmoid([S|D|Ef] @ gate_w + b) ----
    f32x16 acc1[4] = {};
    {
        bf16x8 sfr[8], dfr[8];
        ld8(wbB, gate_fa, 8, l);                                             // b1
        mma8(acc1, wbA, frag_from_pack(efw[0], 0), frag_from_pack(efw[0], 1)); // b0
        ld8(wbA, gate_fa, 16, l);                                            // b2
        mma8(acc1, wbB, frag_from_pack(efw[1], 0), frag_from_pack(efw[1], 1)); // b1
#pragma unroll
        for (int i = 0; i < 8; i++) sfr[i] = *(const bf16x8*)(rS + i * 16 + hh * 8);
        ld8(wbB, gate_fa, 24, l);                                            // b3
        mma8(acc1, wbA, frag_from_pack(efw[2], 0), frag_from_pack(efw[2], 1)); // b2
        ld8(wbA, gate_fa, 32, l);                                            // b4
        mma8(acc1, wbB, frag_from_pack(efw[3], 0), frag_from_pack(efw[3], 1)); // b3
#pragma unroll
        for (int i = 0; i < 8; i++) dfr[i] = *(const bf16x8*)(rD + i * 16 + hh * 8);
        ld8(wbB, gate_fa, 40, l);                                            // b5
        mma8(acc1, wbA, sfr[0], sfr[1]);                                     // b4
        ld8(wbA, gate_fa, 48, l);                                            // b6
        mma8(acc1, wbB, sfr[2], sfr[3]);                                     // b5
        ld8(wbB, gate_fa, 56, l);                                            // b7
        mma8(acc1, wbA, sfr[4], sfr[5]);                                     // b6
        ld8(wbA, gate_fa, 64, l);                                            // b8
        mma8(acc1, wbB, sfr[6], sfr[7]);                                     // b7
        ld8(wbB, gate_fa, 72, l);                                            // b9
        mma8(acc1, wbA, dfr[0], dfr[1]);                                     // b8
        ld8(wbA, gate_fa, 80, l);                                            // b10
        mma8(acc1, wbB, dfr[2], dfr[3]);                                     // b9
        ld8(wbB, gate_fa, 88, l);                                            // b11
        mma8(acc1, wbA, dfr[4], dfr[5]);                                     // b10
        ld8(wbA, c1_fa, 0, l);               // GEMM2 batch0 — hidden under epilogue1
        mma8(acc1, wbB, dfr[6], dfr[7]);                                     // b11
    }

    // ---- epilogue 1: g = sigmoid(acc1+b); S' = s + g*Ef, D' = d + g*Ef ----
    unsigned sw[4][8], dw[4][8];
    {
#pragma unroll
        for (int m = 0; m < 4; m++) {
#pragma unroll
            for (int P = 0; P < 4; P++) {
                int f0 = m * 32 + P * 8 + hh * 4;
                f32x4 gb = *(const f32x4*)&gate_b[f0];
                u32x2 sv = *(const u32x2*)(rS + f0);
                u32x2 dv = *(const u32x2*)(rD + f0);
#pragma unroll
                for (int u2 = 0; u2 < 2; u2++) {
                    int p = P * 2 + u2;
                    unsigned svw = u2 ? sv.y : sv.x;
                    unsigned dvw = u2 ? dv.y : dv.x;
                    float g0 = acc1[m][2 * p] + gb[2 * u2];
                    float g1 = acc1[m][2 * p + 1] + gb[2 * u2 + 1];
                    g0 = 1.f / (1.f + __expf(-g0));
                    g1 = 1.f / (1.f + __expf(-g1));
                    float e0 = bflo(efw[m][p]), e1 = bfhi(efw[m][p]);
                    sw[m][p] = bfpack(bflo(svw) + g0 * e0, bfhi(svw) + g1 * e1);
                    dw[m][p] = bfpack(bflo(dvw) + g0 * e0, bfhi(dvw) + g1 * e1);
                }
            }
        }
    }

    // ---- GEMM2: z1 = relu(LN([S'|D'] @ c1_w + b)) ----
    unsigned z1w[4][8];
    bf16x8 wcA[4], wcB[4];
    {
        f32x16 acc2[4] = {};
        ld8(wbB, c1_fa, 8, l);                                              // b1
        mma8(acc2, wbA, frag_from_pack(sw[0], 0), frag_from_pack(sw[0], 1)); // b0
        ld8(wbA, c1_fa, 16, l);
        mma8(acc2, wbB, frag_from_pack(sw[1], 0), frag_from_pack(sw[1], 1)); // b1
        ld8(wbB, c1_fa, 24, l);
        mma8(acc2, wbA, frag_from_pack(sw[2], 0), frag_from_pack(sw[2], 1)); // b2
        ld8(wbA, c1_fa, 32, l);
        mma8(acc2, wbB, frag_from_pack(sw[3], 0), frag_from_pack(sw[3], 1)); // b3
        ld8(wbB, c1_fa, 40, l);
        mma8(acc2, wbA, frag_from_pack(dw[0], 0), frag_from_pack(dw[0], 1)); // b4
        ld8(wbA, c1_fa, 48, l);
        mma8(acc2, wbB, frag_from_pack(dw[1], 0), frag_from_pack(dw[1], 1)); // b5
        ld8(wbB, c1_fa, 56, l);
        mma8(acc2, wbA, frag_from_pack(dw[2], 0), frag_from_pack(dw[2], 1)); // b6
        ld4(wcA, c2_fa, 0, l);               // GEMM3 batch0 — hidden under LN-pack
        mma8(acc2, wbB, frag_from_pack(dw[3], 0), frag_from_pack(dw[3], 1)); // b7
        bias_ln_relu_pack<4>(acc2, c1_b, cl1_g, cl1_b, hh, 1.f / 128.f, z1w);
    }

    // ---- GEMM3: z2 = relu(LN(z1 @ c2_w + b)); out = z2 @ c3_w + c3_b ----
    {
        f32x16 acc3[2] = {};
        ld4(wcB, c2_fa, 4, l);                                                // b1
        mma4x2(acc3, wcA, frag_from_pack(z1w[0], 0), frag_from_pack(z1w[0], 1)); // b0
        ld4(wcA, c2_fa, 8, l);
        mma4x2(acc3, wcB, frag_from_pack(z1w[1], 0), frag_from_pack(z1w[1], 1)); // b1
        ld4(wcB, c2_fa, 12, l);
        mma4x2(acc3, wcA, frag_from_pack(z1w[2], 0), frag_from_pack(z1w[2], 1)); // b2
        mma4x2(acc3, wcB, frag_from_pack(z1w[3], 0), frag_from_pack(z1w[3], 1)); // b3
        // bias + LN(64) + relu + c3 dot
        float sm = 0.f;
#pragma unroll
        for (int m = 0; m < 2; m++) {
#pragma unroll
            for (int P = 0; P < 4; P++) {
                f32x4 bv = *(const f32x4*)&c2_b[m * 32 + P * 8 + hh * 4];
#pragma unroll
                for (int u = 0; u < 4; u++) {
                    float v = acc3[m][P * 4 + u] + bv[u];
                    acc3[m][P * 4 + u] = v;
                    sm += v;
                }
            }
        }
        sm += __shfl_xor(sm, 32, 64);
        float mean = sm * (1.f / 64.f);
        float q = 0.f;
#pragma unroll
        for (int m = 0; m < 2; m++) {
#pragma unroll
            for (int r = 0; r < 16; r++) { float d = acc3[m][r] - mean; q += d * d; }
        }
        q += __shfl_xor(q, 32, 64);
        float rstd = rsqrtf(q * (1.f / 64.f) + 1e-5f);
        float s0 = 0.f, s1 = 0.f;
#pragma unroll
        for (int m = 0; m < 2; m++) {
#pragma unroll
            for (int P = 0; P < 4; P++) {
                int f0 = m * 32 + P * 8 + hh * 4;
                f32x4 gv = *(const f32x4*)&cl2_g[f0];
                f32x4 bz = *(const f32x4*)&cl2_b[f0];
                f32x4 wA = *(const f32x4*)&c3_w[f0 * 2];
                f32x4 wB = *(const f32x4*)&c3_w[f0 * 2 + 4];
#pragma unroll
                for (int u = 0; u < 4; u++) {
                    float y = fmaxf((acc3[m][P * 4 + u] - mean) * rstd * gv[u] + bz[u], 0.f);
                    float wc0 = (u < 2) ? wA[2 * u] : wB[2 * u - 4];
                    float wc1 = (u < 2) ? wA[2 * u + 1] : wB[2 * u - 3];
                    s0 += y * wc0;
                    s1 += y * wc1;
                }
            }
        }
        s0 += __shfl_xor(s0, 32, 64);
        s1 += __shfl_xor(s1, 32, 64);
        if (hh == 0 && pIdx < E) {
            float2 o; o.x = s0 + c3_b[0]; o.y = s1 + c3_b[1];
            *(float2*)&out[(size_t)eF * 2] = o;
        }
    }
}

extern "C" void kernel_launch(void* const* d_in, const int* in_sizes, int n_in,
                              void* d_out, int out_size, void* d_ws, size_t ws_size,
                              hipStream_t stream) {
    const float* x        = (const float*)d_in[0];
    const int*   eidx     = (const int*)d_in[1];
    const float* eattr    = (const float*)d_in[2];
    const float* ne_w     = (const float*)d_in[3];
    const float* ne_b     = (const float*)d_in[4];
    const float* ne_g     = (const float*)d_in[5];
    const float* ne_beta  = (const float*)d_in[6];
    const float* ee_w     = (const float*)d_in[7];
    const float* ee_b     = (const float*)d_in[8];
    const float* ee_g     = (const float*)d_in[9];
    const float* ee_beta  = (const float*)d_in[10];
    const float* gate_w   = (const float*)d_in[11];
    const float* gate_b   = (const float*)d_in[12];
    const float* gatA_w   = (const float*)d_in[13];
    const float* gatA_as  = (const float*)d_in[14];
    const float* gatA_ad  = (const float*)d_in[15];
    const float* gatA_bias= (const float*)d_in[16];
    const float* gatB_w   = (const float*)d_in[17];
    const float* gatB_as  = (const float*)d_in[18];
    const float* gatB_ad  = (const float*)d_in[19];
    const float* gatB_bias= (const float*)d_in[20];
    const float* ln_g     = (const float*)d_in[21];
    const float* ln_b     = (const float*)d_in[22];
    const float* c1_w     = (const float*)d_in[23];
    const float* c1_b     = (const float*)d_in[24];
    const float* cl1_g    = (const float*)d_in[25];
    const float* cl1_b    = (const float*)d_in[26];
    const float* c2_w     = (const float*)d_in[27];
    const float* c2_b     = (const float*)d_in[28];
    const float* cl2_g    = (const float*)d_in[29];
    const float* cl2_b    = (const float*)d_in[30];
    const float* c3_w     = (const float*)d_in[31];
    const float* c3_b     = (const float*)d_in[32];

    const int N = in_sizes[0] / NFEAT;
    const int E = in_sizes[1] / 2;
    const int E2 = E + N;
    const int* rowp = eidx;
    const int* colp = eidx + E;

    char* ws = (char*)d_ws;
    size_t off = 0;
    auto alloc = [&](size_t bytes) -> void* {
        void* p = ws + off;
        off = (off + bytes + 255) & ~(size_t)255;
        return p;
    };
    int*   deg    = (int*)alloc((size_t)N * 4);
    int*   cursor = (int*)alloc((size_t)N * 4);
    int*   cursor2= (int*)alloc((size_t)N * 4);
    int*   offs   = (int*)alloc((size_t)(N + 1) * 4);
    int*   srcs   = (int*)alloc((size_t)E2 * 4);
    int*   eperm  = (int*)alloc((size_t)E * 4);
    int*   bsum   = (int*)alloc((size_t)1024 * 4);
    float* a_d    = (float*)alloc((size_t)N * 8 * 4);
    __hip_bfloat16* h_bfA  = (__hip_bfloat16*)alloc((size_t)N * H * 2);
    __hip_bfloat16* h_bfB  = (__hip_bfloat16*)alloc((size_t)N * H * 2);
    __hip_bfloat16* xp_bf  = (__hip_bfloat16*)alloc((size_t)N * XPS * 2);
    __hip_bfloat16* gate_sw= (__hip_bfloat16*)alloc((size_t)49152 * 2);
    __hip_bfloat16* c1_sw  = (__hip_bfloat16*)alloc((size_t)32768 * 2);
    __hip_bfloat16* c2_sw  = (__hip_bfloat16*)alloc((size_t)8192 * 2);
    __hip_bfloat16* wT3    = (__hip_bfloat16*)alloc((size_t)3 * 128 * 128 * 2);
    __hip_bfloat16* ee_sw  = (__hip_bfloat16*)alloc((size_t)4096 * 2);
    (void)ws_size;

    // fused front-end: wprep | degree | node_enc (after deg memset)
    const int nbWprep = (141312 + 255) / 256;
    const int nbDeg   = (E2 + 255) / 256;
    const int nbEnc   = (N + 3) / 4;
    hipMemsetAsync(deg, 0, (size_t)N * 4, stream);
    k_front<<<nbWprep + nbDeg + nbEnc, 256, 0, stream>>>(
        gate_w, c1_w, c2_w, gatA_w, gatB_w, ee_w,
        gate_sw, c1_sw, c2_sw, wT3, ee_sw,
        colp, deg,
        x, ne_w, ne_b, ne_g, ne_beta, h_bfA,
        E, N, nbWprep, nbDeg);

    // multi-block exclusive scan of deg -> offs/cursor (+cursor2 = offs - n)
    const int NB = (N + 255) / 256;
    k_scanA<<<NB, 256, 0, stream>>>(deg, bsum, N);
    k_scanB<<<1, 1024, 0, stream>>>(bsum, NB);
    k_scanC<<<NB, 256, 0, stream>>>(deg, bsum, offs, cursor, cursor2, N);
    k_scatter<<<(E2 + 255) / 256, 256, 0, stream>>>(rowp, colp, cursor, cursor2,
                                                    srcs, eperm, E, N);

    int ngrid = (N + 3) / 4;
    int xpgrid = (N + 63) / 64;
    __hip_bfloat16* hin = h_bfA;
    __hip_bfloat16* hout = h_bfB;
    for (int l = 0; l < 2; l++) {
        k_gat_xp_mfma<<<xpgrid, 256, 0, stream>>>(hin, wT3 + (size_t)l * 16384,
                                                  gatA_as + l * H, gatA_ad + l * H,
                                                  xp_bf, a_d, 8, N);
        k_gat_agg<<<ngrid, 256, 0, stream>>>(xp_bf, a_d, offs, srcs,
                                             gatA_bias + l * H, ln_g + l * H, ln_b + l * H,
                                             hout, 8, N);
        __hip_bfloat16* tmp = hin; hin = hout; hout = tmp;
    }
    k_gat_xp_mfma<<<xpgrid, 256, 0, stream>>>(hin, wT3 + (size_t)2 * 16384,
                                              gatB_as, gatB_ad,
                                              xp_bf, a_d, 1, N);
    k_gat_agg<<<ngrid, 256, 0, stream>>>(xp_bf, a_d, offs, srcs,
                                         gatB_bias, ln_g + 2 * H, ln_b + 2 * H,
                                         hout, 1, N);

    // deep-prefetch 32x32 MFMA edge classifier, dst-sorted edge order
    k_edge_cls_mfma32<<<(E + 127) / 128, 256, 0, stream>>>(
        hout, rowp, colp, eperm, eattr,
        ee_sw, ee_b, ee_g, ee_beta,
        gate_sw, gate_b,
        c1_sw, c1_b, cl1_g, cl1_b,
        c2_sw, c2_b, cl2_g, cl2_b,
        c3_w, c3_b,
        (float*)d_out, E);
}

// Round 12
// 557.420 us; speedup vs baseline: 1.0756x; 1.0756x over previous
//
#include <hip/hip_runtime.h>
#include <hip/hip_bf16.h>

#define H 128
#define NFEAT 10
#define EFEAT 10
#define XPS 144   // packed xp row stride in bf16: 128 vals + 8 f32 scores

typedef __attribute__((ext_vector_type(8))) short bf16x8;
typedef __attribute__((ext_vector_type(4))) float f32x4;
typedef __attribute__((ext_vector_type(16))) float f32x16;
typedef __attribute__((ext_vector_type(4))) unsigned u32x4;
typedef __attribute__((ext_vector_type(2))) unsigned u32x2;

__device__ __forceinline__ float bflo(unsigned v) { return __uint_as_float(v << 16); }
__device__ __forceinline__ float bfhi(unsigned v) { return __uint_as_float(v & 0xffff0000u); }
__device__ __forceinline__ unsigned bfpack(float a, float b) {
    __hip_bfloat16 h0 = __float2bfloat16(a), h1 = __float2bfloat16(b);
    return (unsigned)(*(unsigned short*)&h0) | ((unsigned)(*(unsigned short*)&h1) << 16);
}
__device__ __forceinline__ bf16x8 cast8(u32x4 v) { return __builtin_bit_cast(bf16x8, v); }

// Next-GEMM B-fragment from 8 acc-order packed words (verified, absmax 0.015625).
__device__ __forceinline__ bf16x8 frag_from_pack(const unsigned* w, int b2) {
    u32x4 t;
    t.x = w[b2 * 4 + 0];
    t.y = w[b2 * 4 + 1];
    t.z = w[b2 * 4 + 2];
    t.w = w[b2 * 4 + 3];
    return cast8(t);
}

// ---- deep-prefetch helpers: batch weight loads + batch MFMAs ----
__device__ __forceinline__ void ld8(bf16x8* dst, const __hip_bfloat16* base, int slot0, int l) {
#pragma unroll
    for (int i = 0; i < 8; i++)
        dst[i] = *(const bf16x8*)(base + ((size_t)(slot0 + i) * 64 + l) * 8);
}
__device__ __forceinline__ void ld4(bf16x8* dst, const __hip_bfloat16* base, int slot0, int l) {
#pragma unroll
    for (int i = 0; i < 4; i++)
        dst[i] = *(const bf16x8*)(base + ((size_t)(slot0 + i) * 64 + l) * 8);
}
__device__ __forceinline__ void mma8(f32x16* acc, const bf16x8* wb, bf16x8 bb0, bf16x8 bb1) {
#pragma unroll
    for (int mt = 0; mt < 4; mt++)
        acc[mt] = __builtin_amdgcn_mfma_f32_32x32x16_bf16(wb[mt], bb0, acc[mt], 0, 0, 0);
#pragma unroll
    for (int mt = 0; mt < 4; mt++)
        acc[mt] = __builtin_amdgcn_mfma_f32_32x32x16_bf16(wb[4 + mt], bb1, acc[mt], 0, 0, 0);
}
__device__ __forceinline__ void mma4x2(f32x16* acc, const bf16x8* wb, bf16x8 bb0, bf16x8 bb1) {
#pragma unroll
    for (int mt = 0; mt < 2; mt++)
        acc[mt] = __builtin_amdgcn_mfma_f32_32x32x16_bf16(wb[mt], bb0, acc[mt], 0, 0, 0);
#pragma unroll
    for (int mt = 0; mt < 2; mt++)
        acc[mt] = __builtin_amdgcn_mfma_f32_32x32x16_bf16(wb[2 + mt], bb1, acc[mt], 0, 0, 0);
}

// bias + LayerNorm + ReLU on NT 32x32 D-tiles, pack to acc-order bf16 words.
template<int NT>
__device__ __forceinline__ void bias_ln_relu_pack(f32x16* acc, const float* __restrict__ bias,
        const float* __restrict__ g, const float* __restrict__ beta,
        int hh, float invn, unsigned (*pk)[8]) {
    float sm = 0.f;
#pragma unroll
    for (int m = 0; m < NT; m++) {
#pragma unroll
        for (int P = 0; P < 4; P++) {
            f32x4 bv = *(const f32x4*)&bias[m * 32 + P * 8 + hh * 4];
#pragma unroll
            for (int u = 0; u < 4; u++) {
                float v = acc[m][P * 4 + u] + bv[u];
                acc[m][P * 4 + u] = v;
                sm += v;
            }
        }
    }
    sm += __shfl_xor(sm, 32, 64);
    float mean = sm * invn;
    float q = 0.f;
#pragma unroll
    for (int m = 0; m < NT; m++) {
#pragma unroll
        for (int r = 0; r < 16; r++) { float d = acc[m][r] - mean; q += d * d; }
    }
    q += __shfl_xor(q, 32, 64);
    float rstd = rsqrtf(q * invn + 1e-5f);
#pragma unroll
    for (int m = 0; m < NT; m++) {
#pragma unroll
        for (int P = 0; P < 4; P++) {
            f32x4 gv = *(const f32x4*)&g[m * 32 + P * 8 + hh * 4];
            f32x4 bz = *(const f32x4*)&beta[m * 32 + P * 8 + hh * 4];
#pragma unroll
            for (int u = 0; u < 4; u++) {
                float y = fmaxf((acc[m][P * 4 + u] - mean) * rstd * gv[u] + bz[u], 0.f);
                acc[m][P * 4 + u] = y;
            }
        }
    }
#pragma unroll
    for (int m = 0; m < NT; m++) {
#pragma unroll
        for (int p = 0; p < 8; p++) pk[m][p] = bfpack(acc[m][2 * p], acc[m][2 * p + 1]);
    }
}

// ---------------- fused front-end: wprep | degree | node_enc ------------------
__global__ __launch_bounds__(256) void k_front(
        const float* __restrict__ gate_w, const float* __restrict__ c1_w,
        const float* __restrict__ c2_w, const float* __restrict__ gatA_w,
        const float* __restrict__ gatB_w, const float* __restrict__ ee_w,
        __hip_bfloat16* __restrict__ gate_sw, __hip_bfloat16* __restrict__ c1_sw,
        __hip_bfloat16* __restrict__ c2_sw, __hip_bfloat16* __restrict__ wT3,
        __hip_bfloat16* __restrict__ ee_sw,
        const int* __restrict__ colp, int* __restrict__ deg,
        const float* __restrict__ x, const float* __restrict__ ne_w,
        const float* __restrict__ ne_b, const float* __restrict__ ne_g,
        const float* __restrict__ ne_beta, __hip_bfloat16* __restrict__ h,
        int E, int N, int nbWprep, int nbDeg) {
    int blk = blockIdx.x;
    if (blk < nbWprep) {
        int i = blk * 256 + threadIdx.x;
        if (i < 49152) {                       // gate: 96 frags (NMT=4, KS=24)
            int j = i & 7, l = (i >> 3) & 63, s = i >> 9;
            int m = s & 3, ks = s >> 2;
            int hh = l >> 5;
            int k;
            if (ks < 8) k = 256 + ks * 16 + 4 * hh + (j & 3) + 8 * (j >> 2);   // Ef (pack)
            else        k = (ks - 8) * 16 + hh * 8 + j;                         // S|D (mem)
            int n = m * 32 + (l & 31);
            gate_sw[i] = __float2bfloat16(gate_w[k * 128 + n]);
        } else if (i < 81920) {                // c1: 64 frags, pack-sourced
            int mm = i - 49152;
            int j = mm & 7, l = (mm >> 3) & 63, s = mm >> 9;
            int m = s & 3, ks = s >> 2;
            int k = ks * 16 + 4 * (l >> 5) + (j & 3) + 8 * (j >> 2);
            int n = m * 32 + (l & 31);
            c1_sw[mm] = __float2bfloat16(c1_w[k * 128 + n]);
        } else if (i < 90112) {                // c2: 16 frags, pack-sourced
            int mm = i - 81920;
            int j = mm & 7, l = (mm >> 3) & 63, s = mm >> 9;
            int m = s & 1, ks = s >> 1;
            int k = ks * 16 + 4 * (l >> 5) + (j & 3) + 8 * (j >> 2);
            int n = m * 32 + (l & 31);
            c2_sw[mm] = __float2bfloat16(c2_w[k * 64 + n]);
        } else if (i < 139264) {               // gatA[0], gatA[1], gatB
            int m = i - 90112;
            int mat = m / 16384, r = m % 16384;
            int n = r / 128, k = r % 128;
            const float* src = (mat < 2) ? (gatA_w + (size_t)mat * 16384) : gatB_w;
            wT3[m] = __float2bfloat16(src[k * 128 + n]);
        } else if (i < 141312) {               // ee: 4 frags, memory-sourced
            int mm = i - 139264;
            int j = mm & 7, l = (mm >> 3) & 63, s = mm >> 9;
            int k = (l >> 5) * 8 + j;
            int n = s * 32 + (l & 31);
            ee_sw[mm] = (k < EFEAT) ? __float2bfloat16(ee_w[k * 128 + n])
                                    : __float2bfloat16(0.0f);
        }
        return;
    }
    blk -= nbWprep;
    if (blk < nbDeg) {
        int i = blk * 256 + threadIdx.x;
        int E2 = E + N;
        if (i < E2) {
            int d = (i < E) ? colp[i] : (i - E);
            atomicAdd(&deg[d], 1);
        }
        return;
    }
    blk -= nbDeg;
    {
        int t = threadIdx.x;
        int w = t >> 6, l = t & 63;
        int n = blk * 4 + w;
        if (n >= N) return;
        float xs[NFEAT];
#pragma unroll
        for (int k = 0; k < NFEAT; k++) xs[k] = x[(size_t)n * NFEAT + k];
        float a0 = ne_b[2 * l], a1 = ne_b[2 * l + 1];
#pragma unroll
        for (int k = 0; k < NFEAT; k++) {
            float2 wv = *(const float2*)&ne_w[k * H + 2 * l];
            a0 += xs[k] * wv.x;
            a1 += xs[k] * wv.y;
        }
        float p = a0 + a1;
#pragma unroll
        for (int s = 1; s < 64; s <<= 1) p += __shfl_xor(p, s, 64);
        float mean = p * (1.0f / H);
        float d0 = a0 - mean, d1 = a1 - mean;
        float q = d0 * d0 + d1 * d1;
#pragma unroll
        for (int s = 1; s < 64; s <<= 1) q += __shfl_xor(q, s, 64);
        float rstd = rsqrtf(q * (1.0f / H) + 1e-5f);
        float y0 = fmaxf(d0 * rstd * ne_g[2 * l] + ne_beta[2 * l], 0.0f);
        float y1 = fmaxf(d1 * rstd * ne_g[2 * l + 1] + ne_beta[2 * l + 1], 0.0f);
        *(unsigned*)&h[(size_t)n * H + 2 * l] = bfpack(y0, y1);
    }
}

// ---------------- multi-block exclusive scan ----------------
__global__ __launch_bounds__(256) void k_scanA(const int* __restrict__ deg,
                                               int* __restrict__ bsum, int N) {
    __shared__ int s[256];
    int t = threadIdx.x;
    int i = blockIdx.x * 256 + t;
    s[t] = (i < N) ? deg[i] : 0;
    __syncthreads();
    for (int off = 128; off > 0; off >>= 1) {
        if (t < off) s[t] += s[t + off];
        __syncthreads();
    }
    if (t == 0) bsum[blockIdx.x] = s[0];
}

__global__ __launch_bounds__(1024) void k_scanB(int* __restrict__ bsum, int NB) {
    __shared__ int s[1024];
    int t = threadIdx.x;
    int v = (t < NB) ? bsum[t] : 0;
    s[t] = v;
    __syncthreads();
    for (int off = 1; off < 1024; off <<= 1) {
        int u = (t >= off) ? s[t - off] : 0;
        __syncthreads();
        s[t] += u;
        __syncthreads();
    }
    if (t < NB) bsum[t] = s[t] - v;   // exclusive prefix
}

__global__ __launch_bounds__(256) void k_scanC(const int* __restrict__ deg,
                                               const int* __restrict__ bbase,
                                               int* __restrict__ offs,
                                               int* __restrict__ cursor, int N) {
    __shared__ int s[256];
    int t = threadIdx.x;
    int i = blockIdx.x * 256 + t;
    int v = (i < N) ? deg[i] : 0;
    s[t] = v;
    __syncthreads();
    for (int off = 1; off < 256; off <<= 1) {
        int u = (t >= off) ? s[t - off] : 0;
        __syncthreads();
        s[t] += u;
        __syncthreads();
    }
    int incl = s[t];
    int base = bbase[blockIdx.x];
    if (i < N) {
        int e = base + incl - v;
        offs[i] = e;
        cursor[i] = e;
        if (i == N - 1) offs[N] = base + incl;
    }
}

__global__ __launch_bounds__(256) void k_scatter(const int* __restrict__ rowp,
                                                 const int* __restrict__ colp,
                                                 int* __restrict__ cursor,
                                                 int* __restrict__ srcs, int E, int N) {
    int i = blockIdx.x * blockDim.x + threadIdx.x;
    if (i < E + N) {
        int s, d;
        if (i < E) { s = rowp[i]; d = colp[i]; }
        else       { s = i - E;  d = i - E; }
        int pos = atomicAdd(&cursor[d], 1);
        srcs[pos] = s;
    }
}

// ---------------- GAT stage 1: MFMA xp = h@w, fused scores ----------------
__global__ __launch_bounds__(256, 2) void k_gat_xp_mfma(
        const __hip_bfloat16* __restrict__ h_bf,
        const __hip_bfloat16* __restrict__ wT,
        const float* __restrict__ asrc,
        const float* __restrict__ adst,
        __hip_bfloat16* __restrict__ xp_bf,
        float* __restrict__ a_d,
        int heads, int N) {
    __shared__ __hip_bfloat16 Ws[128 * 136];
    __shared__ __hip_bfloat16 As[64 * 136];
    int t = threadIdx.x;
    int n0 = blockIdx.x * 64;

#pragma unroll
    for (int it = 0; it < 2; it++) {
        int idx = it * 256 + t;
        int row = idx >> 2, seg = idx & 3;
        const uint4* src = (const uint4*)(wT + row * 128 + seg * 32);
        uint4 v0 = src[0], v1 = src[1], v2 = src[2], v3 = src[3];
        uint4* dst = (uint4*)&Ws[row * 136 + seg * 32];
        dst[0] = v0; dst[1] = v1; dst[2] = v2; dst[3] = v3;
    }
    {
        int row = t >> 2, seg = t & 3;
        int n = n0 + row; if (n >= N) n = N - 1;
        const uint4* src = (const uint4*)(h_bf + (size_t)n * 128 + seg * 32);
        uint4 v0 = src[0], v1 = src[1], v2 = src[2], v3 = src[3];
        uint4* dst = (uint4*)&As[row * 136 + seg * 32];
        dst[0] = v0; dst[1] = v1; dst[2] = v2; dst[3] = v3;
    }
    __syncthreads();

    int w = t >> 6, l = t & 63, ln15 = l & 15, quad = l >> 4, q8 = quad * 8;
    f32x4 acc[8] = {};
#pragma unroll
    for (int k = 0; k < 128; k += 32) {
        bf16x8 af = *(const bf16x8*)&As[(w * 16 + ln15) * 136 + k + q8];
#pragma unroll
        for (int i = 0; i < 8; i++) {
            bf16x8 bfr = *(const bf16x8*)&Ws[(i * 16 + ln15) * 136 + k + q8];
            acc[i] = __builtin_amdgcn_mfma_f32_16x16x32_bf16(af, bfr, acc[i], 0, 0, 0);
        }
    }

    if (heads == 8) {
#pragma unroll
        for (int i = 0; i < 8; i++) {
            float av = asrc[i * 16 + ln15], dvv = adst[i * 16 + ln15];
            float ps[4], pd[4];
#pragma unroll
            for (int r = 0; r < 4; r++) { ps[r] = acc[i][r] * av; pd[r] = acc[i][r] * dvv; }
#pragma unroll
            for (int s = 1; s < 16; s <<= 1) {
#pragma unroll
                for (int r = 0; r < 4; r++) {
                    ps[r] += __shfl_xor(ps[r], s, 64);
                    pd[r] += __shfl_xor(pd[r], s, 64);
                }
            }
            if (ln15 == 0) {
#pragma unroll
                for (int r = 0; r < 4; r++) {
                    int n = n0 + w * 16 + quad * 4 + r;
                    if (n < N) {
                        *(float*)&xp_bf[(size_t)n * XPS + 128 + 2 * i] = ps[r];
                        a_d[(size_t)n * 8 + i] = pd[r];
                    }
                }
            }
        }
    } else {
        float ps[4] = {0, 0, 0, 0}, pd[4] = {0, 0, 0, 0};
#pragma unroll
        for (int i = 0; i < 8; i++) {
            float av = asrc[i * 16 + ln15], dvv = adst[i * 16 + ln15];
#pragma unroll
            for (int r = 0; r < 4; r++) { ps[r] += acc[i][r] * av; pd[r] += acc[i][r] * dvv; }
        }
#pragma unroll
        for (int s = 1; s < 16; s <<= 1) {
#pragma unroll
            for (int r = 0; r < 4; r++) {
                ps[r] += __shfl_xor(ps[r], s, 64);
                pd[r] += __shfl_xor(pd[r], s, 64);
            }
        }
        if (ln15 == 0) {
#pragma unroll
            for (int r = 0; r < 4; r++) {
                int n = n0 + w * 16 + quad * 4 + r;
                if (n < N) {
                    *(float*)&xp_bf[(size_t)n * XPS + 128] = ps[r];
                    a_d[n] = pd[r];
                }
            }
        }
    }

#pragma unroll
    for (int i = 0; i < 8; i++) {
#pragma unroll
        for (int r = 0; r < 4; r++) {
            int n = n0 + w * 16 + quad * 4 + r;
            if (n < N) xp_bf[(size_t)n * XPS + i * 16 + ln15] = __float2bfloat16(acc[i][r]);
        }
    }
}

// ---------------- GAT stage 2: 1 wave/node, packed-row gather (R8 8-batch) ----
__global__ __launch_bounds__(256) void k_gat_agg(const __hip_bfloat16* __restrict__ xp,
                                                 const float* __restrict__ a_d,
                                                 const int* __restrict__ offs,
                                                 const int* __restrict__ srcs,
                                                 const float* __restrict__ bias,
                                                 const float* __restrict__ g,
                                                 const float* __restrict__ b,
                                                 __hip_bfloat16* __restrict__ hout,
                                                 int heads, int N) {
    int t = threadIdx.x;
    int w = t >> 6, l = t & 63;
    int n = blockIdx.x * 4 + w;
    if (n >= N) return;
    int head = (heads == 8) ? (l >> 3) : 0;
    float adv = a_d[(size_t)n * heads + head];
    int s0 = offs[n], s1 = offs[n + 1];
    float acc0 = 0.0f, acc1 = 0.0f, den = 0.0f;
    int j = s0;
    for (; j + 8 <= s1; j += 8) {
        int s_[8];
#pragma unroll
        for (int u = 0; u < 8; u++) s_[u] = srcs[j + u];
        float e_[8]; unsigned v_[8];
#pragma unroll
        for (int u = 0; u < 8; u++) {
            const __hip_bfloat16* xr = xp + (size_t)s_[u] * XPS;
            e_[u] = ((const float*)xr)[64 + head];
            v_[u] = *(const unsigned*)&xr[2 * l];
        }
#pragma unroll
        for (int u = 0; u < 8; u++) {
            float e = e_[u] + adv;
            e = (e >= 0.0f) ? e : 0.2f * e;
            float ex = __expf(e);
            den += ex;
            acc0 += ex * bflo(v_[u]);
            acc1 += ex * bfhi(v_[u]);
        }
    }
    for (; j + 4 <= s1; j += 4) {
        int s_[4];
#pragma unroll
        for (int u = 0; u < 4; u++) s_[u] = srcs[j + u];
        float e_[4]; unsigned v_[4];
#pragma unroll
        for (int u = 0; u < 4; u++) {
            const __hip_bfloat16* xr = xp + (size_t)s_[u] * XPS;
            e_[u] = ((const float*)xr)[64 + head];
            v_[u] = *(const unsigned*)&xr[2 * l];
        }
#pragma unroll
        for (int u = 0; u < 4; u++) {
            float e = e_[u] + adv;
            e = (e >= 0.0f) ? e : 0.2f * e;
            float ex = __expf(e);
            den += ex;
            acc0 += ex * bflo(v_[u]);
            acc1 += ex * bfhi(v_[u]);
        }
    }
    for (; j < s1; j++) {
        int s = srcs[j];
        const __hip_bfloat16* xr = xp + (size_t)s * XPS;
        float e = ((const float*)xr)[64 + head] + adv;
        e = (e >= 0.0f) ? e : 0.2f * e;
        float ex = __expf(e);
        den += ex;
        unsigned v = *(const unsigned*)&xr[2 * l];
        acc0 += ex * bflo(v);
        acc1 += ex * bfhi(v);
    }
    float inv = 1.0f / den;
    float v0 = acc0 * inv + bias[2 * l];
    float v1 = acc1 * inv + bias[2 * l + 1];
    float p = v0 + v1;
#pragma unroll
    for (int s = 1; s < 64; s <<= 1) p += __shfl_xor(p, s, 64);
    float mean = p * (1.0f / H);
    float d0 = v0 - mean, d1 = v1 - mean;
    float q = d0 * d0 + d1 * d1;
#pragma unroll
    for (int s = 1; s < 64; s <<= 1) q += __shfl_xor(q, s, 64);
    float rstd = rsqrtf(q * (1.0f / H) + 1e-5f);
    float y0 = fmaxf(d0 * rstd * g[2 * l] + b[2 * l], 0.0f);
    float y1 = fmaxf(d1 * rstd * g[2 * l + 1] + b[2 * l + 1], 0.0f);
    *(unsigned*)&hout[(size_t)n * H + 2 * l] = bfpack(y0, y1);
}

// ---------------- Edge classifier (R4 config — best measured: 223 µs) --------
// Deep-prefetch 32x32 MFMA chain; register-resident activations; no LDS;
// identity edge order (R11's dst-sorted order regressed: eattr/out scatter
// cost more than the rD locality won — h_bf is L2/L3-resident anyway).
__global__ __launch_bounds__(256, 2) void k_edge_cls_mfma32(
        const __hip_bfloat16* __restrict__ h_bf,
        const int* __restrict__ rowp, const int* __restrict__ colp,
        const float* __restrict__ eattr,
        const __hip_bfloat16* __restrict__ ee_fa, const float* __restrict__ ee_b,
        const float* __restrict__ ee_g, const float* __restrict__ ee_beta,
        const __hip_bfloat16* __restrict__ gate_fa, const float* __restrict__ gate_b,
        const __hip_bfloat16* __restrict__ c1_fa, const float* __restrict__ c1_b,
        const float* __restrict__ cl1_g, const float* __restrict__ cl1_b,
        const __hip_bfloat16* __restrict__ c2_fa, const float* __restrict__ c2_b,
        const float* __restrict__ cl2_g, const float* __restrict__ cl2_b,
        const float* __restrict__ c3_w, const float* __restrict__ c3_b,
        float* __restrict__ out, int E) {
    int t = threadIdx.x;
    int w = t >> 6, l = t & 63;
    int hh = l >> 5, e32 = l & 31;
    int eIdx = blockIdx.x * 128 + w * 32 + e32;
    int eF = (eIdx < E) ? eIdx : (E - 1);
    int ri = rowp[eF], ci = colp[eF];
    const unsigned short* rS = (const unsigned short*)h_bf + (size_t)ri * H;
    const unsigned short* rD = (const unsigned short*)h_bf + (size_t)ci * H;

    bf16x8 wbA[8], wbB[8];

    // ---- GEMM0: Ef = relu(LN(ea @ ee_w + ee_b)), kept as packed words efw ----
    unsigned efw[4][8];
    {
        const char* eb = (const char*)(eattr + (size_t)eF * EFEAT);
        float2 p0 = *(const float2*)(eb + (hh << 5));
        float2 p1 = *(const float2*)(eb + 8);
        float2 p2 = *(const float2*)(eb + 16);
        float2 p3 = *(const float2*)(eb + 24);
        bf16x8 eef[4];
        ld4(eef, ee_fa, 0, l);
        if (hh) { p1.x = p1.y = 0.f; p2.x = p2.y = 0.f; p3.x = p3.y = 0.f; }
        u32x4 bwv;
        bwv.x = bfpack(p0.x, p0.y);
        bwv.y = bfpack(p1.x, p1.y);
        bwv.z = bfpack(p2.x, p2.y);
        bwv.w = bfpack(p3.x, p3.y);
        bf16x8 bb = cast8(bwv);
        f32x16 acc[4] = {};
#pragma unroll
        for (int m = 0; m < 4; m++)
            acc[m] = __builtin_amdgcn_mfma_f32_32x32x16_bf16(eef[m], bb, acc[m], 0, 0, 0);
        ld8(wbA, gate_fa, 0, l);             // GEMM1 batch0 — hidden under LN-pack
        bias_ln_relu_pack<4>(acc, ee_b, ee_g, ee_beta, hh, 1.f / 128.f, efw);
    }

    // ---- GEMM1: gate = sigmoid([S|D|Ef] @ gate_w + b) ----
    f32x16 acc1[4] = {};
    {
        bf16x8 sfr[8], dfr[8];
        ld8(wbB, gate_fa, 8, l);                                             // b1
        mma8(acc1, wbA, frag_from_pack(efw[0], 0), frag_from_pack(efw[0], 1)); // b0
        ld8(wbA, gate_fa, 16, l);                                            // b2
        mma8(acc1, wbB, frag_from_pack(efw[1], 0), frag_from_pack(efw[1], 1)); // b1
#pragma unroll
        for (int i = 0; i < 8; i++) sfr[i] = *(const bf16x8*)(rS + i * 16 + hh * 8);
        ld8(wbB, gate_fa, 24, l);                                            // b3
        mma8(acc1, wbA, frag_from_pack(efw[2], 0), frag_from_pack(efw[2], 1)); // b2
        ld8(wbA, gate_fa, 32, l);                                            // b4
        mma8(acc1, wbB, frag_from_pack(efw[3], 0), frag_from_pack(efw[3], 1)); // b3
#pragma unroll
        for (int i = 0; i < 8; i++) dfr[i] = *(const bf16x8*)(rD + i * 16 + hh * 8);
        ld8(wbB, gate_fa, 40, l);                                            // b5
        mma8(acc1, wbA, sfr[0], sfr[1]);                                     // b4
        ld8(wbA, gate_fa, 48, l);                                            // b6
        mma8(acc1, wbB, sfr[2], sfr[3]);                                     // b5
        ld8(wbB, gate_fa, 56, l);                                            // b7
        mma8(acc1, wbA, sfr[4], sfr[5]);                                     // b6
        ld8(wbA, gate_fa, 64, l);                                            // b8
        mma8(acc1, wbB, sfr[6], sfr[7]);                                     // b7
        ld8(wbB, gate_fa, 72, l);                                            // b9
        mma8(acc1, wbA, dfr[0], dfr[1]);                                     // b8
        ld8(wbA, gate_fa, 80, l);                                            // b10
        mma8(acc1, wbB, dfr[2], dfr[3]);                                     // b9
        ld8(wbB, gate_fa, 88, l);                                            // b11
        mma8(acc1, wbA, dfr[4], dfr[5]);                                     // b10
        ld8(wbA, c1_fa, 0, l);               // GEMM2 batch0 — hidden under epilogue1
        mma8(acc1, wbB, dfr[6], dfr[7]);                                     // b11
    }

    // ---- epilogue 1: g = sigmoid(acc1+b); S' = s + g*Ef, D' = d + g*Ef ----
    unsigned sw[4][8], dw[4][8];
    {
#pragma unroll
        for (int m = 0; m < 4; m++) {
#pragma unroll
            for (int P = 0; P < 4; P++) {
                int f0 = m * 32 + P * 8 + hh * 4;
                f32x4 gb = *(const f32x4*)&gate_b[f0];
                u32x2 sv = *(const u32x2*)(rS + f0);
                u32x2 dv = *(const u32x2*)(rD + f0);
#pragma unroll
                for (int u2 = 0; u2 < 2; u2++) {
                    int p = P * 2 + u2;
                    unsigned svw = u2 ? sv.y : sv.x;
                    unsigned dvw = u2 ? dv.y : dv.x;
                    float g0 = acc1[m][2 * p] + gb[2 * u2];
                    float g1 = acc1[m][2 * p + 1] + gb[2 * u2 + 1];
                    g0 = 1.f / (1.f + __expf(-g0));
                    g1 = 1.f / (1.f + __expf(-g1));
                    float e0 = bflo(efw[m][p]), e1 = bfhi(efw[m][p]);
                    sw[m][p] = bfpack(bflo(svw) + g0 * e0, bfhi(svw) + g1 * e1);
                    dw[m][p] = bfpack(bflo(dvw) + g0 * e0, bfhi(dvw) + g1 * e1);
                }
            }
        }
    }

    // ---- GEMM2: z1 = relu(LN([S'|D'] @ c1_w + b)) ----
    unsigned z1w[4][8];
    bf16x8 wcA[4], wcB[4];
    {
        f32x16 acc2[4] = {};
        ld8(wbB, c1_fa, 8, l);                                              // b1
        mma8(acc2, wbA, frag_from_pack(sw[0], 0), frag_from_pack(sw[0], 1)); // b0
        ld8(wbA, c1_fa, 16, l);
        mma8(acc2, wbB, frag_from_pack(sw[1], 0), frag_from_pack(sw[1], 1)); // b1
        ld8(wbB, c1_fa, 24, l);
        mma8(acc2, wbA, frag_from_pack(sw[2], 0), frag_from_pack(sw[2], 1)); // b2
        ld8(wbA, c1_fa, 32, l);
        mma8(acc2, wbB, frag_from_pack(sw[3], 0), frag_from_pack(sw[3], 1)); // b3
        ld8(wbB, c1_fa, 40, l);
        mma8(acc2, wbA, frag_from_pack(dw[0], 0), frag_from_pack(dw[0], 1)); // b4
        ld8(wbA, c1_fa, 48, l);
        mma8(acc2, wbB, frag_from_pack(dw[1], 0), frag_from_pack(dw[1], 1)); // b5
        ld8(wbB, c1_fa, 56, l);
        mma8(acc2, wbA, frag_from_pack(dw[2], 0), frag_from_pack(dw[2], 1)); // b6
        ld4(wcA, c2_fa, 0, l);               // GEMM3 batch0 — hidden under LN-pack
        mma8(acc2, wbB, frag_from_pack(dw[3], 0), frag_from_pack(dw[3], 1)); // b7
        bias_ln_relu_pack<4>(acc2, c1_b, cl1_g, cl1_b, hh, 1.f / 128.f, z1w);
    }

    // ---- GEMM3: z2 = relu(LN(z1 @ c2_w + b)); out = z2 @ c3_w + c3_b ----
    {
        f32x16 acc3[2] = {};
        ld4(wcB, c2_fa, 4, l);                                                // b1
        mma4x2(acc3, wcA, frag_from_pack(z1w[0], 0), frag_from_pack(z1w[0], 1)); // b0
        ld4(wcA, c2_fa, 8, l);
        mma4x2(acc3, wcB, frag_from_pack(z1w[1], 0), frag_from_pack(z1w[1], 1)); // b1
        ld4(wcB, c2_fa, 12, l);
        mma4x2(acc3, wcA, frag_from_pack(z1w[2], 0), frag_from_pack(z1w[2], 1)); // b2
        mma4x2(acc3, wcB, frag_from_pack(z1w[3], 0), frag_from_pack(z1w[3], 1)); // b3
        // bias + LN(64) + relu + c3 dot
        float sm = 0.f;
#pragma unroll
        for (int m = 0; m < 2; m++) {
#pragma unroll
            for (int P = 0; P < 4; P++) {
                f32x4 bv = *(const f32x4*)&c2_b[m * 32 + P * 8 + hh * 4];
#pragma unroll
                for (int u = 0; u < 4; u++) {
                    float v = acc3[m][P * 4 + u] + bv[u];
                    acc3[m][P * 4 + u] = v;
                    sm += v;
                }
            }
        }
        sm += __shfl_xor(sm, 32, 64);
        float mean = sm * (1.f / 64.f);
        float q = 0.f;
#pragma unroll
        for (int m = 0; m < 2; m++) {
#pragma unroll
            for (int r = 0; r < 16; r++) { float d = acc3[m][r] - mean; q += d * d; }
        }
        q += __shfl_xor(q, 32, 64);
        float rstd = rsqrtf(q * (1.f / 64.f) + 1e-5f);
        float s0 = 0.f, s1 = 0.f;
#pragma unroll
        for (int m = 0; m < 2; m++) {
#pragma unroll
            for (int P = 0; P < 4; P++) {
                int f0 = m * 32 + P * 8 + hh * 4;
                f32x4 gv = *(const f32x4*)&cl2_g[f0];
                f32x4 bz = *(const f32x4*)&cl2_b[f0];
                f32x4 wA = *(const f32x4*)&c3_w[f0 * 2];
                f32x4 wB = *(const f32x4*)&c3_w[f0 * 2 + 4];
#pragma unroll
                for (int u = 0; u < 4; u++) {
                    float y = fmaxf((acc3[m][P * 4 + u] - mean) * rstd * gv[u] + bz[u], 0.f);
                    float wc0 = (u < 2) ? wA[2 * u] : wB[2 * u - 4];
                    float wc1 = (u < 2) ? wA[2 * u + 1] : wB[2 * u - 3];
                    s0 += y * wc0;
                    s1 += y * wc1;
                }
            }
        }
        s0 += __shfl_xor(s0, 32, 64);
        s1 += __shfl_xor(s1, 32, 64);
        if (hh == 0 && eIdx < E) {
            float2 o; o.x = s0 + c3_b[0]; o.y = s1 + c3_b[1];
            *(float2*)&out[(size_t)eIdx * 2] = o;
        }
    }
}

extern "C" void kernel_launch(void* const* d_in, const int* in_sizes, int n_in,
                              void* d_out, int out_size, void* d_ws, size_t ws_size,
                              hipStream_t stream) {
    const float* x        = (const float*)d_in[0];
    const int*   eidx     = (const int*)d_in[1];
    const float* eattr    = (const float*)d_in[2];
    const float* ne_w     = (const float*)d_in[3];
    const float* ne_b     = (const float*)d_in[4];
    const float* ne_g     = (const float*)d_in[5];
    const float* ne_beta  = (const float*)d_in[6];
    const float* ee_w     = (const float*)d_in[7];
    const float* ee_b     = (const float*)d_in[8];
    const float* ee_g     = (const float*)d_in[9];
    const float* ee_beta  = (const float*)d_in[10];
    const float* gate_w   = (const float*)d_in[11];
    const float* gate_b   = (const float*)d_in[12];
    const float* gatA_w   = (const float*)d_in[13];
    const float* gatA_as  = (const float*)d_in[14];
    const float* gatA_ad  = (const float*)d_in[15];
    const float* gatA_bias= (const float*)d_in[16];
    const float* gatB_w   = (const float*)d_in[17];
    const float* gatB_as  = (const float*)d_in[18];
    const float* gatB_ad  = (const float*)d_in[19];
    const float* gatB_bias= (const float*)d_in[20];
    const float* ln_g     = (const float*)d_in[21];
    const float* ln_b     = (const float*)d_in[22];
    const float* c1_w     = (const float*)d_in[23];
    const float* c1_b     = (const float*)d_in[24];
    const float* cl1_g    = (const float*)d_in[25];
    const float* cl1_b    = (const float*)d_in[26];
    const float* c2_w     = (const float*)d_in[27];
    const float* c2_b     = (const float*)d_in[28];
    const float* cl2_g    = (const float*)d_in[29];
    const float* cl2_b    = (const float*)d_in[30];
    const float* c3_w     = (const float*)d_in[31];
    const float* c3_b     = (const float*)d_in[32];

    const int N = in_sizes[0] / NFEAT;
    const int E = in_sizes[1] / 2;
    const int E2 = E + N;
    const int* rowp = eidx;
    const int* colp = eidx + E;

    char* ws = (char*)d_ws;
    size_t off = 0;
    auto alloc = [&](size_t bytes) -> void* {
        void* p = ws + off;
        off = (off + bytes + 255) & ~(size_t)255;
        return p;
    };
    int*   deg    = (int*)alloc((size_t)N * 4);
    int*   cursor = (int*)alloc((size_t)N * 4);
    int*   offs   = (int*)alloc((size_t)(N + 1) * 4);
    int*   srcs   = (int*)alloc((size_t)E2 * 4);
    int*   bsum   = (int*)alloc((size_t)1024 * 4);
    float* a_d    = (float*)alloc((size_t)N * 8 * 4);
    __hip_bfloat16* h_bfA  = (__hip_bfloat16*)alloc((size_t)N * H * 2);
    __hip_bfloat16* h_bfB  = (__hip_bfloat16*)alloc((size_t)N * H * 2);
    __hip_bfloat16* xp_bf  = (__hip_bfloat16*)alloc((size_t)N * XPS * 2);
    __hip_bfloat16* gate_sw= (__hip_bfloat16*)alloc((size_t)49152 * 2);
    __hip_bfloat16* c1_sw  = (__hip_bfloat16*)alloc((size_t)32768 * 2);
    __hip_bfloat16* c2_sw  = (__hip_bfloat16*)alloc((size_t)8192 * 2);
    __hip_bfloat16* wT3    = (__hip_bfloat16*)alloc((size_t)3 * 128 * 128 * 2);
    __hip_bfloat16* ee_sw  = (__hip_bfloat16*)alloc((size_t)4096 * 2);
    (void)ws_size;

    // fused front-end: wprep | degree | node_enc (after deg memset)
    const int nbWprep = (141312 + 255) / 256;
    const int nbDeg   = (E2 + 255) / 256;
    const int nbEnc   = (N + 3) / 4;
    hipMemsetAsync(deg, 0, (size_t)N * 4, stream);
    k_front<<<nbWprep + nbDeg + nbEnc, 256, 0, stream>>>(
        gate_w, c1_w, c2_w, gatA_w, gatB_w, ee_w,
        gate_sw, c1_sw, c2_sw, wT3, ee_sw,
        colp, deg,
        x, ne_w, ne_b, ne_g, ne_beta, h_bfA,
        E, N, nbWprep, nbDeg);

    // multi-block exclusive scan of deg -> offs/cursor
    const int NB = (N + 255) / 256;
    k_scanA<<<NB, 256, 0, stream>>>(deg, bsum, N);
    k_scanB<<<1, 1024, 0, stream>>>(bsum, NB);
    k_scanC<<<NB, 256, 0, stream>>>(deg, bsum, offs, cursor, N);
    k_scatter<<<(E2 + 255) / 256, 256, 0, stream>>>(rowp, colp, cursor, srcs, E, N);

    int ngrid = (N + 3) / 4;
    int xpgrid = (N + 63) / 64;
    __hip_bfloat16* hin = h_bfA;
    __hip_bfloat16* hout = h_bfB;
    for (int l = 0; l < 2; l++) {
        k_gat_xp_mfma<<<xpgrid, 256, 0, stream>>>(hin, wT3 + (size_t)l * 16384,
                                                  gatA_as + l * H, gatA_ad + l * H,
                                                  xp_bf, a_d, 8, N);
        k_gat_agg<<<ngrid, 256, 0, stream>>>(xp_bf, a_d, offs, srcs,
                                             gatA_bias + l * H, ln_g + l * H, ln_b + l * H,
                                             hout, 8, N);
        __hip_bfloat16* tmp = hin; hin = hout; hout = tmp;
    }
    k_gat_xp_mfma<<<xpgrid, 256, 0, stream>>>(hin, wT3 + (size_t)2 * 16384,
                                              gatB_as, gatB_ad,
                                              xp_bf, a_d, 1, N);
    k_gat_agg<<<ngrid, 256, 0, stream>>>(xp_bf, a_d, offs, srcs,
                                         gatB_bias, ln_g + 2 * H, ln_b + 2 * H,
                                         hout, 1, N);

    // deep-prefetch 32x32 MFMA edge classifier (R4 config, identity order)
    k_edge_cls_mfma32<<<(E + 127) / 128, 256, 0, stream>>>(
        hout, rowp, colp, eattr,
        ee_sw, ee_b, ee_g, ee_beta,
        gate_sw, gate_b,
        c1_sw, c1_b, cl1_g, cl1_b,
        c2_sw, c2_b, cl2_g, cl2_b,
        c3_w, c3_b,
        (float*)d_out, E);
}

// Round 13
// 553.957 us; speedup vs baseline: 1.0823x; 1.0063x over previous
//
#include <hip/hip_runtime.h>
#include <hip/hip_bf16.h>

#define H 128
#define NFEAT 10
#define EFEAT 10
#define XPS 144   // packed xp row stride in bf16: 128 vals + 8 f32 scores

typedef __attribute__((ext_vector_type(8))) short bf16x8;
typedef __attribute__((ext_vector_type(4))) float f32x4;
typedef __attribute__((ext_vector_type(16))) float f32x16;
typedef __attribute__((ext_vector_type(4))) unsigned u32x4;
typedef __attribute__((ext_vector_type(2))) unsigned u32x2;

__device__ __forceinline__ float bflo(unsigned v) { return __uint_as_float(v << 16); }
__device__ __forceinline__ float bfhi(unsigned v) { return __uint_as_float(v & 0xffff0000u); }
__device__ __forceinline__ unsigned bfpack(float a, float b) {
    __hip_bfloat16 h0 = __float2bfloat16(a), h1 = __float2bfloat16(b);
    return (unsigned)(*(unsigned short*)&h0) | ((unsigned)(*(unsigned short*)&h1) << 16);
}
__device__ __forceinline__ bf16x8 cast8(u32x4 v) { return __builtin_bit_cast(bf16x8, v); }

// Next-GEMM B-fragment from 8 acc-order packed words (verified, absmax 0.015625).
__device__ __forceinline__ bf16x8 frag_from_pack(const unsigned* w, int b2) {
    u32x4 t;
    t.x = w[b2 * 4 + 0];
    t.y = w[b2 * 4 + 1];
    t.z = w[b2 * 4 + 2];
    t.w = w[b2 * 4 + 3];
    return cast8(t);
}

// ---- slim ping-pong weight batches (R13: 32 VGPR FIFO instead of 64) ----
__device__ __forceinline__ void ld4(bf16x8* dst, const __hip_bfloat16* base, int slot0, int l) {
#pragma unroll
    for (int i = 0; i < 4; i++)
        dst[i] = *(const bf16x8*)(base + ((size_t)(slot0 + i) * 64 + l) * 8);
}
__device__ __forceinline__ void ld2(bf16x8* dst, const __hip_bfloat16* base, int slot0, int l) {
#pragma unroll
    for (int i = 0; i < 2; i++)
        dst[i] = *(const bf16x8*)(base + ((size_t)(slot0 + i) * 64 + l) * 8);
}
// one ks-step (NMT=4): 4 MFMAs sharing one B-fragment.
__device__ __forceinline__ void mma4n4(f32x16* acc, const bf16x8* wb, bf16x8 bb) {
#pragma unroll
    for (int mt = 0; mt < 4; mt++)
        acc[mt] = __builtin_amdgcn_mfma_f32_32x32x16_bf16(wb[mt], bb, acc[mt], 0, 0, 0);
}
// one ks-step (NMT=2): 2 MFMAs sharing one B-fragment.
__device__ __forceinline__ void mma2n2(f32x16* acc, const bf16x8* wb, bf16x8 bb) {
#pragma unroll
    for (int mt = 0; mt < 2; mt++)
        acc[mt] = __builtin_amdgcn_mfma_f32_32x32x16_bf16(wb[mt], bb, acc[mt], 0, 0, 0);
}

// bias + LayerNorm + ReLU on NT 32x32 D-tiles, pack to acc-order bf16 words.
template<int NT>
__device__ __forceinline__ void bias_ln_relu_pack(f32x16* acc, const float* __restrict__ bias,
        const float* __restrict__ g, const float* __restrict__ beta,
        int hh, float invn, unsigned (*pk)[8]) {
    float sm = 0.f;
#pragma unroll
    for (int m = 0; m < NT; m++) {
#pragma unroll
        for (int P = 0; P < 4; P++) {
            f32x4 bv = *(const f32x4*)&bias[m * 32 + P * 8 + hh * 4];
#pragma unroll
            for (int u = 0; u < 4; u++) {
                float v = acc[m][P * 4 + u] + bv[u];
                acc[m][P * 4 + u] = v;
                sm += v;
            }
        }
    }
    sm += __shfl_xor(sm, 32, 64);
    float mean = sm * invn;
    float q = 0.f;
#pragma unroll
    for (int m = 0; m < NT; m++) {
#pragma unroll
        for (int r = 0; r < 16; r++) { float d = acc[m][r] - mean; q += d * d; }
    }
    q += __shfl_xor(q, 32, 64);
    float rstd = rsqrtf(q * invn + 1e-5f);
#pragma unroll
    for (int m = 0; m < NT; m++) {
#pragma unroll
        for (int P = 0; P < 4; P++) {
            f32x4 gv = *(const f32x4*)&g[m * 32 + P * 8 + hh * 4];
            f32x4 bz = *(const f32x4*)&beta[m * 32 + P * 8 + hh * 4];
#pragma unroll
            for (int u = 0; u < 4; u++) {
                float y = fmaxf((acc[m][P * 4 + u] - mean) * rstd * gv[u] + bz[u], 0.f);
                acc[m][P * 4 + u] = y;
            }
        }
    }
#pragma unroll
    for (int m = 0; m < NT; m++) {
#pragma unroll
        for (int p = 0; p < 8; p++) pk[m][p] = bfpack(acc[m][2 * p], acc[m][2 * p + 1]);
    }
}

// ---------------- fused front-end: wprep | degree | node_enc ------------------
__global__ __launch_bounds__(256) void k_front(
        const float* __restrict__ gate_w, const float* __restrict__ c1_w,
        const float* __restrict__ c2_w, const float* __restrict__ gatA_w,
        const float* __restrict__ gatB_w, const float* __restrict__ ee_w,
        __hip_bfloat16* __restrict__ gate_sw, __hip_bfloat16* __restrict__ c1_sw,
        __hip_bfloat16* __restrict__ c2_sw, __hip_bfloat16* __restrict__ wT3,
        __hip_bfloat16* __restrict__ ee_sw,
        const int* __restrict__ colp, int* __restrict__ deg,
        const float* __restrict__ x, const float* __restrict__ ne_w,
        const float* __restrict__ ne_b, const float* __restrict__ ne_g,
        const float* __restrict__ ne_beta, __hip_bfloat16* __restrict__ h,
        int E, int N, int nbWprep, int nbDeg) {
    int blk = blockIdx.x;
    if (blk < nbWprep) {
        int i = blk * 256 + threadIdx.x;
        if (i < 49152) {                       // gate: 96 frags (NMT=4, KS=24)
            int j = i & 7, l = (i >> 3) & 63, s = i >> 9;
            int m = s & 3, ks = s >> 2;
            int hh = l >> 5;
            int k;
            if (ks < 8) k = 256 + ks * 16 + 4 * hh + (j & 3) + 8 * (j >> 2);   // Ef (pack)
            else        k = (ks - 8) * 16 + hh * 8 + j;                         // S|D (mem)
            int n = m * 32 + (l & 31);
            gate_sw[i] = __float2bfloat16(gate_w[k * 128 + n]);
        } else if (i < 81920) {                // c1: 64 frags, pack-sourced
            int mm = i - 49152;
            int j = mm & 7, l = (mm >> 3) & 63, s = mm >> 9;
            int m = s & 3, ks = s >> 2;
            int k = ks * 16 + 4 * (l >> 5) + (j & 3) + 8 * (j >> 2);
            int n = m * 32 + (l & 31);
            c1_sw[mm] = __float2bfloat16(c1_w[k * 128 + n]);
        } else if (i < 90112) {                // c2: 16 frags, pack-sourced
            int mm = i - 81920;
            int j = mm & 7, l = (mm >> 3) & 63, s = mm >> 9;
            int m = s & 1, ks = s >> 1;
            int k = ks * 16 + 4 * (l >> 5) + (j & 3) + 8 * (j >> 2);
            int n = m * 32 + (l & 31);
            c2_sw[mm] = __float2bfloat16(c2_w[k * 64 + n]);
        } else if (i < 139264) {               // gatA[0], gatA[1], gatB
            int m = i - 90112;
            int mat = m / 16384, r = m % 16384;
            int n = r / 128, k = r % 128;
            const float* src = (mat < 2) ? (gatA_w + (size_t)mat * 16384) : gatB_w;
            wT3[m] = __float2bfloat16(src[k * 128 + n]);
        } else if (i < 141312) {               // ee: 4 frags, memory-sourced
            int mm = i - 139264;
            int j = mm & 7, l = (mm >> 3) & 63, s = mm >> 9;
            int k = (l >> 5) * 8 + j;
            int n = s * 32 + (l & 31);
            ee_sw[mm] = (k < EFEAT) ? __float2bfloat16(ee_w[k * 128 + n])
                                    : __float2bfloat16(0.0f);
        }
        return;
    }
    blk -= nbWprep;
    if (blk < nbDeg) {
        int i = blk * 256 + threadIdx.x;
        int E2 = E + N;
        if (i < E2) {
            int d = (i < E) ? colp[i] : (i - E);
            atomicAdd(&deg[d], 1);
        }
        return;
    }
    blk -= nbDeg;
    {
        int t = threadIdx.x;
        int w = t >> 6, l = t & 63;
        int n = blk * 4 + w;
        if (n >= N) return;
        float xs[NFEAT];
#pragma unroll
        for (int k = 0; k < NFEAT; k++) xs[k] = x[(size_t)n * NFEAT + k];
        float a0 = ne_b[2 * l], a1 = ne_b[2 * l + 1];
#pragma unroll
        for (int k = 0; k < NFEAT; k++) {
            float2 wv = *(const float2*)&ne_w[k * H + 2 * l];
            a0 += xs[k] * wv.x;
            a1 += xs[k] * wv.y;
        }
        float p = a0 + a1;
#pragma unroll
        for (int s = 1; s < 64; s <<= 1) p += __shfl_xor(p, s, 64);
        float mean = p * (1.0f / H);
        float d0 = a0 - mean, d1 = a1 - mean;
        float q = d0 * d0 + d1 * d1;
#pragma unroll
        for (int s = 1; s < 64; s <<= 1) q += __shfl_xor(q, s, 64);
        float rstd = rsqrtf(q * (1.0f / H) + 1e-5f);
        float y0 = fmaxf(d0 * rstd * ne_g[2 * l] + ne_beta[2 * l], 0.0f);
        float y1 = fmaxf(d1 * rstd * ne_g[2 * l + 1] + ne_beta[2 * l + 1], 0.0f);
        *(unsigned*)&h[(size_t)n * H + 2 * l] = bfpack(y0, y1);
    }
}

// ---------------- multi-block exclusive scan ----------------
__global__ __launch_bounds__(256) void k_scanA(const int* __restrict__ deg,
                                               int* __restrict__ bsum, int N) {
    __shared__ int s[256];
    int t = threadIdx.x;
    int i = blockIdx.x * 256 + t;
    s[t] = (i < N) ? deg[i] : 0;
    __syncthreads();
    for (int off = 128; off > 0; off >>= 1) {
        if (t < off) s[t] += s[t + off];
        __syncthreads();
    }
    if (t == 0) bsum[blockIdx.x] = s[0];
}

__global__ __launch_bounds__(1024) void k_scanB(int* __restrict__ bsum, int NB) {
    __shared__ int s[1024];
    int t = threadIdx.x;
    int v = (t < NB) ? bsum[t] : 0;
    s[t] = v;
    __syncthreads();
    for (int off = 1; off < 1024; off <<= 1) {
        int u = (t >= off) ? s[t - off] : 0;
        __syncthreads();
        s[t] += u;
        __syncthreads();
    }
    if (t < NB) bsum[t] = s[t] - v;   // exclusive prefix
}

__global__ __launch_bounds__(256) void k_scanC(const int* __restrict__ deg,
                                               const int* __restrict__ bbase,
                                               int* __restrict__ offs,
                                               int* __restrict__ cursor, int N) {
    __shared__ int s[256];
    int t = threadIdx.x;
    int i = blockIdx.x * 256 + t;
    int v = (i < N) ? deg[i] : 0;
    s[t] = v;
    __syncthreads();
    for (int off = 1; off < 256; off <<= 1) {
        int u = (t >= off) ? s[t - off] : 0;
        __syncthreads();
        s[t] += u;
        __syncthreads();
    }
    int incl = s[t];
    int base = bbase[blockIdx.x];
    if (i < N) {
        int e = base + incl - v;
        offs[i] = e;
        cursor[i] = e;
        if (i == N - 1) offs[N] = base + incl;
    }
}

__global__ __launch_bounds__(256) void k_scatter(const int* __restrict__ rowp,
                                                 const int* __restrict__ colp,
                                                 int* __restrict__ cursor,
                                                 int* __restrict__ srcs, int E, int N) {
    int i = blockIdx.x * blockDim.x + threadIdx.x;
    if (i < E + N) {
        int s, d;
        if (i < E) { s = rowp[i]; d = colp[i]; }
        else       { s = i - E;  d = i - E; }
        int pos = atomicAdd(&cursor[d], 1);
        srcs[pos] = s;
    }
}

// ---------------- GAT stage 1: MFMA xp = h@w, fused scores ----------------
__global__ __launch_bounds__(256, 2) void k_gat_xp_mfma(
        const __hip_bfloat16* __restrict__ h_bf,
        const __hip_bfloat16* __restrict__ wT,
        const float* __restrict__ asrc,
        const float* __restrict__ adst,
        __hip_bfloat16* __restrict__ xp_bf,
        float* __restrict__ a_d,
        int heads, int N) {
    __shared__ __hip_bfloat16 Ws[128 * 136];
    __shared__ __hip_bfloat16 As[64 * 136];
    int t = threadIdx.x;
    int n0 = blockIdx.x * 64;

#pragma unroll
    for (int it = 0; it < 2; it++) {
        int idx = it * 256 + t;
        int row = idx >> 2, seg = idx & 3;
        const uint4* src = (const uint4*)(wT + row * 128 + seg * 32);
        uint4 v0 = src[0], v1 = src[1], v2 = src[2], v3 = src[3];
        uint4* dst = (uint4*)&Ws[row * 136 + seg * 32];
        dst[0] = v0; dst[1] = v1; dst[2] = v2; dst[3] = v3;
    }
    {
        int row = t >> 2, seg = t & 3;
        int n = n0 + row; if (n >= N) n = N - 1;
        const uint4* src = (const uint4*)(h_bf + (size_t)n * 128 + seg * 32);
        uint4 v0 = src[0], v1 = src[1], v2 = src[2], v3 = src[3];
        uint4* dst = (uint4*)&As[row * 136 + seg * 32];
        dst[0] = v0; dst[1] = v1; dst[2] = v2; dst[3] = v3;
    }
    __syncthreads();

    int w = t >> 6, l = t & 63, ln15 = l & 15, quad = l >> 4, q8 = quad * 8;
    f32x4 acc[8] = {};
#pragma unroll
    for (int k = 0; k < 128; k += 32) {
        bf16x8 af = *(const bf16x8*)&As[(w * 16 + ln15) * 136 + k + q8];
#pragma unroll
        for (int i = 0; i < 8; i++) {
            bf16x8 bfr = *(const bf16x8*)&Ws[(i * 16 + ln15) * 136 + k + q8];
            acc[i] = __builtin_amdgcn_mfma_f32_16x16x32_bf16(af, bfr, acc[i], 0, 0, 0);
        }
    }

    if (heads == 8) {
#pragma unroll
        for (int i = 0; i < 8; i++) {
            float av = asrc[i * 16 + ln15], dvv = adst[i * 16 + ln15];
            float ps[4], pd[4];
#pragma unroll
            for (int r = 0; r < 4; r++) { ps[r] = acc[i][r] * av; pd[r] = acc[i][r] * dvv; }
#pragma unroll
            for (int s = 1; s < 16; s <<= 1) {
#pragma unroll
                for (int r = 0; r < 4; r++) {
                    ps[r] += __shfl_xor(ps[r], s, 64);
                    pd[r] += __shfl_xor(pd[r], s, 64);
                }
            }
            if (ln15 == 0) {
#pragma unroll
                for (int r = 0; r < 4; r++) {
                    int n = n0 + w * 16 + quad * 4 + r;
                    if (n < N) {
                        *(float*)&xp_bf[(size_t)n * XPS + 128 + 2 * i] = ps[r];
                        a_d[(size_t)n * 8 + i] = pd[r];
                    }
                }
            }
        }
    } else {
        float ps[4] = {0, 0, 0, 0}, pd[4] = {0, 0, 0, 0};
#pragma unroll
        for (int i = 0; i < 8; i++) {
            float av = asrc[i * 16 + ln15], dvv = adst[i * 16 + ln15];
#pragma unroll
            for (int r = 0; r < 4; r++) { ps[r] += acc[i][r] * av; pd[r] += acc[i][r] * dvv; }
        }
#pragma unroll
        for (int s = 1; s < 16; s <<= 1) {
#pragma unroll
            for (int r = 0; r < 4; r++) {
                ps[r] += __shfl_xor(ps[r], s, 64);
                pd[r] += __shfl_xor(pd[r], s, 64);
            }
        }
        if (ln15 == 0) {
#pragma unroll
            for (int r = 0; r < 4; r++) {
                int n = n0 + w * 16 + quad * 4 + r;
                if (n < N) {
                    *(float*)&xp_bf[(size_t)n * XPS + 128] = ps[r];
                    a_d[n] = pd[r];
                }
            }
        }
    }

#pragma unroll
    for (int i = 0; i < 8; i++) {
#pragma unroll
        for (int r = 0; r < 4; r++) {
            int n = n0 + w * 16 + quad * 4 + r;
            if (n < N) xp_bf[(size_t)n * XPS + i * 16 + ln15] = __float2bfloat16(acc[i][r]);
        }
    }
}

// ---------------- GAT stage 2: 1 wave/node, packed-row gather (R8 8-batch) ----
__global__ __launch_bounds__(256) void k_gat_agg(const __hip_bfloat16* __restrict__ xp,
                                                 const float* __restrict__ a_d,
                                                 const int* __restrict__ offs,
                                                 const int* __restrict__ srcs,
                                                 const float* __restrict__ bias,
                                                 const float* __restrict__ g,
                                                 const float* __restrict__ b,
                                                 __hip_bfloat16* __restrict__ hout,
                                                 int heads, int N) {
    int t = threadIdx.x;
    int w = t >> 6, l = t & 63;
    int n = blockIdx.x * 4 + w;
    if (n >= N) return;
    int head = (heads == 8) ? (l >> 3) : 0;
    float adv = a_d[(size_t)n * heads + head];
    int s0 = offs[n], s1 = offs[n + 1];
    float acc0 = 0.0f, acc1 = 0.0f, den = 0.0f;
    int j = s0;
    for (; j + 8 <= s1; j += 8) {
        int s_[8];
#pragma unroll
        for (int u = 0; u < 8; u++) s_[u] = srcs[j + u];
        float e_[8]; unsigned v_[8];
#pragma unroll
        for (int u = 0; u < 8; u++) {
            const __hip_bfloat16* xr = xp + (size_t)s_[u] * XPS;
            e_[u] = ((const float*)xr)[64 + head];
            v_[u] = *(const unsigned*)&xr[2 * l];
        }
#pragma unroll
        for (int u = 0; u < 8; u++) {
            float e = e_[u] + adv;
            e = (e >= 0.0f) ? e : 0.2f * e;
            float ex = __expf(e);
            den += ex;
            acc0 += ex * bflo(v_[u]);
            acc1 += ex * bfhi(v_[u]);
        }
    }
    for (; j + 4 <= s1; j += 4) {
        int s_[4];
#pragma unroll
        for (int u = 0; u < 4; u++) s_[u] = srcs[j + u];
        float e_[4]; unsigned v_[4];
#pragma unroll
        for (int u = 0; u < 4; u++) {
            const __hip_bfloat16* xr = xp + (size_t)s_[u] * XPS;
            e_[u] = ((const float*)xr)[64 + head];
            v_[u] = *(const unsigned*)&xr[2 * l];
        }
#pragma unroll
        for (int u = 0; u < 4; u++) {
            float e = e_[u] + adv;
            e = (e >= 0.0f) ? e : 0.2f * e;
            float ex = __expf(e);
            den += ex;
            acc0 += ex * bflo(v_[u]);
            acc1 += ex * bfhi(v_[u]);
        }
    }
    for (; j < s1; j++) {
        int s = srcs[j];
        const __hip_bfloat16* xr = xp + (size_t)s * XPS;
        float e = ((const float*)xr)[64 + head] + adv;
        e = (e >= 0.0f) ? e : 0.2f * e;
        float ex = __expf(e);
        den += ex;
        unsigned v = *(const unsigned*)&xr[2 * l];
        acc0 += ex * bflo(v);
        acc1 += ex * bfhi(v);
    }
    float inv = 1.0f / den;
    float v0 = acc0 * inv + bias[2 * l];
    float v1 = acc1 * inv + bias[2 * l + 1];
    float p = v0 + v1;
#pragma unroll
    for (int s = 1; s < 64; s <<= 1) p += __shfl_xor(p, s, 64);
    float mean = p * (1.0f / H);
    float d0 = v0 - mean, d1 = v1 - mean;
    float q = d0 * d0 + d1 * d1;
#pragma unroll
    for (int s = 1; s < 64; s <<= 1) q += __shfl_xor(q, s, 64);
    float rstd = rsqrtf(q * (1.0f / H) + 1e-5f);
    float y0 = fmaxf(d0 * rstd * g[2 * l] + b[2 * l], 0.0f);
    float y1 = fmaxf(d1 * rstd * g[2 * l + 1] + b[2 * l + 1], 0.0f);
    *(unsigned*)&hout[(size_t)n * H + 2 * l] = bfpack(y0, y1);
}

// ---------------- Edge classifier (R13: slim FIFO for 3 waves/SIMD) ----------
// Same math/order as R4/R8/R12 (absmax-identical). Weight FIFO shrunk from
// 2x ld8 (64 VGPR) to ping-pong ld4 (32 VGPR): unified reg demand ~188 -> ~156,
// which fits 3 waves/SIMD under (256,2). R4-vs-R3 showed deep prefetch was
// worth only ~3%, so the shallower FIFO costs little; +50% waves buys latency
// hiding on the random node-row gathers.
__global__ __launch_bounds__(256, 2) void k_edge_cls_mfma32(
        const __hip_bfloat16* __restrict__ h_bf,
        const int* __restrict__ rowp, const int* __restrict__ colp,
        const float* __restrict__ eattr,
        const __hip_bfloat16* __restrict__ ee_fa, const float* __restrict__ ee_b,
        const float* __restrict__ ee_g, const float* __restrict__ ee_beta,
        const __hip_bfloat16* __restrict__ gate_fa, const float* __restrict__ gate_b,
        const __hip_bfloat16* __restrict__ c1_fa, const float* __restrict__ c1_b,
        const float* __restrict__ cl1_g, const float* __restrict__ cl1_b,
        const __hip_bfloat16* __restrict__ c2_fa, const float* __restrict__ c2_b,
        const float* __restrict__ cl2_g, const float* __restrict__ cl2_b,
        const float* __restrict__ c3_w, const float* __restrict__ c3_b,
        float* __restrict__ out, int E) {
    int t = threadIdx.x;
    int w = t >> 6, l = t & 63;
    int hh = l >> 5, e32 = l & 31;
    int eIdx = blockIdx.x * 128 + w * 32 + e32;
    int eF = (eIdx < E) ? eIdx : (E - 1);
    int ri = rowp[eF], ci = colp[eF];
    const unsigned short* rS = (const unsigned short*)h_bf + (size_t)ri * H;
    const unsigned short* rD = (const unsigned short*)h_bf + (size_t)ci * H;

    bf16x8 wb[2][4];           // ping-pong weight batches (one ks each)

    // ---- GEMM0: Ef = relu(LN(ea @ ee_w + ee_b)), kept as packed words efw ----
    unsigned efw[4][8];
    {
        const char* eb = (const char*)(eattr + (size_t)eF * EFEAT);
        float2 p0 = *(const float2*)(eb + (hh << 5));
        float2 p1 = *(const float2*)(eb + 8);
        float2 p2 = *(const float2*)(eb + 16);
        float2 p3 = *(const float2*)(eb + 24);
        bf16x8 eef[4];
        ld4(eef, ee_fa, 0, l);
        if (hh) { p1.x = p1.y = 0.f; p2.x = p2.y = 0.f; p3.x = p3.y = 0.f; }
        u32x4 bwv;
        bwv.x = bfpack(p0.x, p0.y);
        bwv.y = bfpack(p1.x, p1.y);
        bwv.z = bfpack(p2.x, p2.y);
        bwv.w = bfpack(p3.x, p3.y);
        bf16x8 bb = cast8(bwv);
        f32x16 acc[4] = {};
#pragma unroll
        for (int m = 0; m < 4; m++)
            acc[m] = __builtin_amdgcn_mfma_f32_32x32x16_bf16(eef[m], bb, acc[m], 0, 0, 0);
        ld4(wb[0], gate_fa, 0, l);           // GEMM1 ks0 batch — hidden under LN-pack
        bias_ln_relu_pack<4>(acc, ee_b, ee_g, ee_beta, hh, 1.f / 128.f, efw);
    }

    // ---- GEMM1: gate = sigmoid([S|D|Ef] @ gate_w + b), 24 ks ----
    f32x16 acc1[4] = {};
    {
        bf16x8 sfr[8], dfr[8];
#pragma unroll
        for (int ks = 0; ks < 24; ks++) {
            if (ks == 2) {
#pragma unroll
                for (int i = 0; i < 8; i++) sfr[i] = *(const bf16x8*)(rS + i * 16 + hh * 8);
            }
            if (ks == 10) {
#pragma unroll
                for (int i = 0; i < 8; i++) dfr[i] = *(const bf16x8*)(rD + i * 16 + hh * 8);
            }
            if (ks < 23) ld4(wb[(ks + 1) & 1], gate_fa, (ks + 1) * 4, l);
            else         ld4(wb[(ks + 1) & 1], c1_fa, 0, l);   // GEMM2 ks0 prefetch
            bf16x8 bb;
            if (ks < 8)       bb = frag_from_pack(efw[ks >> 1], ks & 1);
            else if (ks < 16) bb = sfr[ks - 8];
            else              bb = dfr[ks - 16];
            mma4n4(acc1, wb[ks & 1], bb);
        }
    }

    // ---- epilogue 1: g = sigmoid(acc1+b); S' = s + g*Ef, D' = d + g*Ef ----
    unsigned sw[4][8], dw[4][8];
    {
#pragma unroll
        for (int m = 0; m < 4; m++) {
#pragma unroll
            for (int P = 0; P < 4; P++) {
                int f0 = m * 32 + P * 8 + hh * 4;
                f32x4 gb = *(const f32x4*)&gate_b[f0];
                u32x2 sv = *(const u32x2*)(rS + f0);
                u32x2 dv = *(const u32x2*)(rD + f0);
#pragma unroll
                for (int u2 = 0; u2 < 2; u2++) {
                    int p = P * 2 + u2;
                    unsigned svw = u2 ? sv.y : sv.x;
                    unsigned dvw = u2 ? dv.y : dv.x;
                    float g0 = acc1[m][2 * p] + gb[2 * u2];
                    float g1 = acc1[m][2 * p + 1] + gb[2 * u2 + 1];
                    g0 = 1.f / (1.f + __expf(-g0));
                    g1 = 1.f / (1.f + __expf(-g1));
                    float e0 = bflo(efw[m][p]), e1 = bfhi(efw[m][p]);
                    sw[m][p] = bfpack(bflo(svw) + g0 * e0, bfhi(svw) + g1 * e1);
                    dw[m][p] = bfpack(bflo(dvw) + g0 * e0, bfhi(dvw) + g1 * e1);
                }
            }
        }
    }

    // ---- GEMM2: z1 = relu(LN([S'|D'] @ c1_w + b)), 16 ks ----
    unsigned z1w[4][8];
    bf16x8 wc[2][2];           // GEMM3 ping-pong batches
    {
        f32x16 acc2[4] = {};
#pragma unroll
        for (int ks = 0; ks < 16; ks++) {
            if (ks < 15) ld4(wb[(ks + 1) & 1], c1_fa, (ks + 1) * 4, l);
            else         ld2(wc[0], c2_fa, 0, l);              // GEMM3 ks0 prefetch
            bf16x8 bb = (ks < 8) ? frag_from_pack(sw[ks >> 1], ks & 1)
                                 : frag_from_pack(dw[(ks - 8) >> 1], ks & 1);
            mma4n4(acc2, wb[ks & 1], bb);
        }
        bias_ln_relu_pack<4>(acc2, c1_b, cl1_g, cl1_b, hh, 1.f / 128.f, z1w);
    }

    // ---- GEMM3: z2 = relu(LN(z1 @ c2_w + b)); out = z2 @ c3_w + c3_b ----
    {
        f32x16 acc3[2] = {};
#pragma unroll
        for (int ks = 0; ks < 8; ks++) {
            if (ks < 7) ld2(wc[(ks + 1) & 1], c2_fa, (ks + 1) * 2, l);
            bf16x8 bb = frag_from_pack(z1w[ks >> 1], ks & 1);
            mma2n2(acc3, wc[ks & 1], bb);
        }
        // bias + LN(64) + relu + c3 dot
        float sm = 0.f;
#pragma unroll
        for (int m = 0; m < 2; m++) {
#pragma unroll
            for (int P = 0; P < 4; P++) {
                f32x4 bv = *(const f32x4*)&c2_b[m * 32 + P * 8 + hh * 4];
#pragma unroll
                for (int u = 0; u < 4; u++) {
                    float v = acc3[m][P * 4 + u] + bv[u];
                    acc3[m][P * 4 + u] = v;
                    sm += v;
                }
            }
        }
        sm += __shfl_xor(sm, 32, 64);
        float mean = sm * (1.f / 64.f);
        float q = 0.f;
#pragma unroll
        for (int m = 0; m < 2; m++) {
#pragma unroll
            for (int r = 0; r < 16; r++) { float d = acc3[m][r] - mean; q += d * d; }
        }
        q += __shfl_xor(q, 32, 64);
        float rstd = rsqrtf(q * (1.f / 64.f) + 1e-5f);
        float s0 = 0.f, s1 = 0.f;
#pragma unroll
        for (int m = 0; m < 2; m++) {
#pragma unroll
            for (int P = 0; P < 4; P++) {
                int f0 = m * 32 + P * 8 + hh * 4;
                f32x4 gv = *(const f32x4*)&cl2_g[f0];
                f32x4 bz = *(const f32x4*)&cl2_b[f0];
                f32x4 wA = *(const f32x4*)&c3_w[f0 * 2];
                f32x4 wB = *(const f32x4*)&c3_w[f0 * 2 + 4];
#pragma unroll
                for (int u = 0; u < 4; u++) {
                    float y = fmaxf((acc3[m][P * 4 + u] - mean) * rstd * gv[u] + bz[u], 0.f);
                    float wc0 = (u < 2) ? wA[2 * u] : wB[2 * u - 4];
                    float wc1 = (u < 2) ? wA[2 * u + 1] : wB[2 * u - 3];
                    s0 += y * wc0;
                    s1 += y * wc1;
                }
            }
        }
        s0 += __shfl_xor(s0, 32, 64);
        s1 += __shfl_xor(s1, 32, 64);
        if (hh == 0 && eIdx < E) {
            float2 o; o.x = s0 + c3_b[0]; o.y = s1 + c3_b[1];
            *(float2*)&out[(size_t)eIdx * 2] = o;
        }
    }
}

extern "C" void kernel_launch(void* const* d_in, const int* in_sizes, int n_in,
                              void* d_out, int out_size, void* d_ws, size_t ws_size,
                              hipStream_t stream) {
    const float* x        = (const float*)d_in[0];
    const int*   eidx     = (const int*)d_in[1];
    const float* eattr    = (const float*)d_in[2];
    const float* ne_w     = (const float*)d_in[3];
    const float* ne_b     = (const float*)d_in[4];
    const float* ne_g     = (const float*)d_in[5];
    const float* ne_beta  = (const float*)d_in[6];
    const float* ee_w     = (const float*)d_in[7];
    const float* ee_b     = (const float*)d_in[8];
    const float* ee_g     = (const float*)d_in[9];
    const float* ee_beta  = (const float*)d_in[10];
    const float* gate_w   = (const float*)d_in[11];
    const float* gate_b   = (const float*)d_in[12];
    const float* gatA_w   = (const float*)d_in[13];
    const float* gatA_as  = (const float*)d_in[14];
    const float* gatA_ad  = (const float*)d_in[15];
    const float* gatA_bias= (const float*)d_in[16];
    const float* gatB_w   = (const float*)d_in[17];
    const float* gatB_as  = (const float*)d_in[18];
    const float* gatB_ad  = (const float*)d_in[19];
    const float* gatB_bias= (const float*)d_in[20];
    const float* ln_g     = (const float*)d_in[21];
    const float* ln_b     = (const float*)d_in[22];
    const float* c1_w     = (const float*)d_in[23];
    const float* c1_b     = (const float*)d_in[24];
    const float* cl1_g    = (const float*)d_in[25];
    const float* cl1_b    = (const float*)d_in[26];
    const float* c2_w     = (const float*)d_in[27];
    const float* c2_b     = (const float*)d_in[28];
    const float* cl2_g    = (const float*)d_in[29];
    const float* cl2_b    = (const float*)d_in[30];
    const float* c3_w     = (const float*)d_in[31];
    const float* c3_b     = (const float*)d_in[32];

    const int N = in_sizes[0] / NFEAT;
    const int E = in_sizes[1] / 2;
    const int E2 = E + N;
    const int* rowp = eidx;
    const int* colp = eidx + E;

    char* ws = (char*)d_ws;
    size_t off = 0;
    auto alloc = [&](size_t bytes) -> void* {
        void* p = ws + off;
        off = (off + bytes + 255) & ~(size_t)255;
        return p;
    };
    int*   deg    = (int*)alloc((size_t)N * 4);
    int*   cursor = (int*)alloc((size_t)N * 4);
    int*   offs   = (int*)alloc((size_t)(N + 1) * 4);
    int*   srcs   = (int*)alloc((size_t)E2 * 4);
    int*   bsum   = (int*)alloc((size_t)1024 * 4);
    float* a_d    = (float*)alloc((size_t)N * 8 * 4);
    __hip_bfloat16* h_bfA  = (__hip_bfloat16*)alloc((size_t)N * H * 2);
    __hip_bfloat16* h_bfB  = (__hip_bfloat16*)alloc((size_t)N * H * 2);
    __hip_bfloat16* xp_bf  = (__hip_bfloat16*)alloc((size_t)N * XPS * 2);
    __hip_bfloat16* gate_sw= (__hip_bfloat16*)alloc((size_t)49152 * 2);
    __hip_bfloat16* c1_sw  = (__hip_bfloat16*)alloc((size_t)32768 * 2);
    __hip_bfloat16* c2_sw  = (__hip_bfloat16*)alloc((size_t)8192 * 2);
    __hip_bfloat16* wT3    = (__hip_bfloat16*)alloc((size_t)3 * 128 * 128 * 2);
    __hip_bfloat16* ee_sw  = (__hip_bfloat16*)alloc((size_t)4096 * 2);
    (void)ws_size;

    // fused front-end: wprep | degree | node_enc (after deg memset)
    const int nbWprep = (141312 + 255) / 256;
    const int nbDeg   = (E2 + 255) / 256;
    const int nbEnc   = (N + 3) / 4;
    hipMemsetAsync(deg, 0, (size_t)N * 4, stream);
    k_front<<<nbWprep + nbDeg + nbEnc, 256, 0, stream>>>(
        gate_w, c1_w, c2_w, gatA_w, gatB_w, ee_w,
        gate_sw, c1_sw, c2_sw, wT3, ee_sw,
        colp, deg,
        x, ne_w, ne_b, ne_g, ne_beta, h_bfA,
        E, N, nbWprep, nbDeg);

    // multi-block exclusive scan of deg -> offs/cursor
    const int NB = (N + 255) / 256;
    k_scanA<<<NB, 256, 0, stream>>>(deg, bsum, N);
    k_scanB<<<1, 1024, 0, stream>>>(bsum, NB);
    k_scanC<<<NB, 256, 0, stream>>>(deg, bsum, offs, cursor, N);
    k_scatter<<<(E2 + 255) / 256, 256, 0, stream>>>(rowp, colp, cursor, srcs, E, N);

    int ngrid = (N + 3) / 4;
    int xpgrid = (N + 63) / 64;
    __hip_bfloat16* hin = h_bfA;
    __hip_bfloat16* hout = h_bfB;
    for (int l = 0; l < 2; l++) {
        k_gat_xp_mfma<<<xpgrid, 256, 0, stream>>>(hin, wT3 + (size_t)l * 16384,
                                                  gatA_as + l * H, gatA_ad + l * H,
                                                  xp_bf, a_d, 8, N);
        k_gat_agg<<<ngrid, 256, 0, stream>>>(xp_bf, a_d, offs, srcs,
                                             gatA_bias + l * H, ln_g + l * H, ln_b + l * H,
                                             hout, 8, N);
        __hip_bfloat16* tmp = hin; hin = hout; hout = tmp;
    }
    k_gat_xp_mfma<<<xpgrid, 256, 0, stream>>>(hin, wT3 + (size_t)2 * 16384,
                                              gatB_as, gatB_ad,
                                              xp_bf, a_d, 1, N);
    k_gat_agg<<<ngrid, 256, 0, stream>>>(xp_bf, a_d, offs, srcs,
                                         gatB_bias, ln_g + 2 * H, ln_b + 2 * H,
                                         hout, 1, N);

    // slim-FIFO 32x32 MFMA edge classifier (R13)
    k_edge_cls_mfma32<<<(E + 127) / 128, 256, 0, stream>>>(
        hout, rowp, colp, eattr,
        ee_sw, ee_b, ee_g, ee_beta,
        gate_sw, gate_b,
        c1_sw, c1_b, cl1_g, cl1_b,
        c2_sw, c2_b, cl2_g, cl2_b,
        c3_w, c3_b,
        (float*)d_out, E);
}